// Round 13
// baseline (347.779 us; speedup 1.0000x reference)
//
#include <hip/hip_runtime.h>
#include <hip/hip_bf16.h>

#define DT_C 0.1f
#define PS 72            // bf16 plane row stride (halves)

typedef short bfrag __attribute__((ext_vector_type(8)));     // 8 bf16
typedef _Float16 hfrag __attribute__((ext_vector_type(8)));  // 8 fp16
typedef float f32x4 __attribute__((ext_vector_type(4)));

union FU { bfrag v; unsigned short s[8]; uint4 q; };
union HU { hfrag v; unsigned short s[8]; uint4 q; };

__device__ __forceinline__ unsigned short bf16_rn(float x) {
  union { float f; unsigned u; } v; v.f = x;
  unsigned r = v.u + 0x7fffu + ((v.u >> 16) & 1u);
  return (unsigned short)(r >> 16);
}
__device__ __forceinline__ float bf16_tof(unsigned short h) {
  union { unsigned u; float f; } v; v.u = ((unsigned)h) << 16; return v.f;
}
__device__ __forceinline__ unsigned short bfu(float x) {
  union { __hip_bfloat16 b; unsigned short u; } cv;
  cv.b = __float2bfloat16(x);
  return cv.u;
}
__device__ __forceinline__ float tanh_f(float x) {
  return 1.0f - 2.0f / (__expf(2.0f * x) + 1.0f);
}
__device__ __forceinline__ void h16split(float v, unsigned short& hu, unsigned short& lu) {
  union { _Float16 h; unsigned short u; } a, b;
  a.h = (_Float16)v;
  b.h = (_Float16)(v - (float)a.h);
  hu = a.u; lu = b.u;
}
__device__ __forceinline__ unsigned short h16hi(float v) {
  union { _Float16 h; unsigned short u; } a; a.h = (_Float16)v; return a.u;
}

// ---- fused weight prep: Wc2->W2 (18432), Wc3->W3 (73728), Wh->WT (12288),
//      We->WeT (8192), Wx->WxT (12288), Wc1->W1T (1024, K padded 27->32) ----
__global__ __launch_bounds__(256) void wprep_k(const float* __restrict__ Wc2,
                                               const float* __restrict__ Wc3,
                                               const float* __restrict__ Wh,
                                               const float* __restrict__ We,
                                               const float* __restrict__ Wx,
                                               const float* __restrict__ Wc1,
                                               unsigned short* __restrict__ W2h,
                                               unsigned short* __restrict__ W2l,
                                               unsigned short* __restrict__ W3h,
                                               unsigned short* __restrict__ W3l,
                                               unsigned short* __restrict__ WTh,
                                               unsigned short* __restrict__ WTl,
                                               unsigned short* __restrict__ WeTh,
                                               unsigned short* __restrict__ WeTl,
                                               unsigned short* __restrict__ WxTh,
                                               unsigned short* __restrict__ WxTl,
                                               unsigned short* __restrict__ W1h,
                                               unsigned short* __restrict__ W1l) {
  int i = blockIdx.x * 256 + threadIdx.x;
  if (i < 18432) {
    int oc = i / 288, rem = i % 288, pos = rem >> 5, ic = rem & 31;
    float v = Wc2[oc*288 + ic*9 + pos];
    h16split(v, W2h[i], W2l[i]);
  } else if (i < 92160) {
    int j = i - 18432;
    int oc = j / 576, rem = j % 576, pos = rem >> 6, ic = rem & 63;
    float v = Wc3[oc*576 + ic*9 + pos];
    h16split(v, W3h[j], W3l[j]);
  } else if (i < 104448) {
    int j = i - 92160;
    int k3 = j >> 12, rem = j & 4095, din = rem >> 6, dout = rem & 63;
    float v = Wh[j];
    unsigned short hi = bf16_rn(v);
    WTh[k3*4096 + dout*64 + din] = hi;
    WTl[k3*4096 + dout*64 + din] = bf16_rn(v - bf16_tof(hi));
  } else if (i < 112640) {
    int j = i - 104448;                    // WeT[e][oc] hi/lo from We[oc][e]
    int e = j >> 7, oc = j & 127;
    float v = We[oc*64 + e];
    h16split(v, WeTh[j], WeTl[j]);
  } else if (i < 124928) {
    int j = i - 112640;                    // WxT[k3][e][din] bf16 hi/lo
    int k3 = j >> 12, rem = j & 4095, e = rem >> 6, din = rem & 63;
    float v = Wx[k3*4096 + din*64 + e];
    unsigned short hi = bf16_rn(v);
    WxTh[j] = hi;
    WxTl[j] = bf16_rn(v - bf16_tof(hi));
  } else if (i < 125952) {
    int j = i - 124928;                    // W1T[oc][k] k=pos*3+ic, pad 27->32
    int oc = j >> 5, k = j & 31;
    float v = 0.f;
    if (k < 27) { int pos = k / 3, ic = k % 3; v = Wc1[oc*27 + ic*9 + pos]; }
    h16split(v, W1h[j], W1l[j]);
  }
}

#define MFMAH(a, bb, cc) __builtin_amdgcn_mfma_f32_16x16x32_f16((a), (bb), (cc), 0, 0, 0)

// ---- conv1 implicit-GEMM MFMA: M=1024 pix, N=32 oc, K=27->32 (k=pos*3+ic) ----
__global__ __launch_bounds__(512) void conv1m_k(const float* __restrict__ frames,
                                                const unsigned short* __restrict__ W1h,
                                                const unsigned short* __restrict__ W1l,
                                                const float* __restrict__ bias,
                                                unsigned short* __restrict__ c1h) {
  __shared__ __align__(16) unsigned short sIn[12288];   // fp16 [3][64][64], 24 KB
  int bt = blockIdx.x, tid = threadIdx.x;
  {
    const float4* src = (const float4*)(frames + (size_t)bt * 12288);
    for (int i = tid; i < 3072; i += 512) {
      float4 v = src[i];
      ushort4 h;
      h.x = h16hi(v.x); h.y = h16hi(v.y); h.z = h16hi(v.z); h.w = h16hi(v.w);
      *(ushort4*)&sIn[i*4] = h;
    }
  }
  __syncthreads();
  int lane = tid & 63, w = tid >> 6, g = lane >> 4, c = lane & 15;
  HU Bh[2], Bl[2];
  #pragma unroll
  for (int n = 0; n < 2; ++n) {
    Bh[n].q = *(const uint4*)(W1h + (n*16 + c)*32 + g*8);
    Bl[n].q = *(const uint4*)(W1l + (n*16 + c)*32 + g*8);
  }
  float bv[2] = {bias[c], bias[16 + c]};
  #pragma unroll 1
  for (int im = 0; im < 8; ++im) {
    int mi = w*8 + im;
    int p = mi*16 + c;
    int ho = p >> 5, wo = p & 31;
    HU Af;
    #pragma unroll
    for (int j = 0; j < 8; ++j) {
      int k = 8*g + j;
      unsigned short v = 0;
      if (k < 27) {
        int pos = k / 3, ic = k % 3;
        int hi = 2*ho - 1 + pos/3, wi = 2*wo - 1 + pos%3;
        v = (hi >= 0 && wi >= 0) ? sIn[ic*4096 + hi*64 + wi] : (unsigned short)0;
      }
      Af.s[j] = v;
    }
    f32x4 acc[2] = {{0.f,0.f,0.f,0.f},{0.f,0.f,0.f,0.f}};
    #pragma unroll
    for (int n = 0; n < 2; ++n) {
      acc[n] = MFMAH(Af.v, Bh[n].v, acc[n]);
      acc[n] = MFMAH(Af.v, Bl[n].v, acc[n]);
    }
    #pragma unroll
    for (int n = 0; n < 2; ++n) {
      int oc = n*16 + c;
      int ks3 = oc >> 3, il = oc & 7;
      #pragma unroll
      for (int r = 0; r < 4; ++r) {
        int po = mi*16 + 4*g + r;
        int ho2 = po >> 5, wo2 = po & 31;
        float v = fmaxf(acc[n][r] + bv[n], 0.f);
        size_t dst = (size_t)bt*32768 + ks3*8192
                   + ((size_t)((ho2*2 + (wo2&1))*16 + (wo2>>1)))*8 + il;
        c1h[dst] = h16hi(v);
      }
    }
  }
}

// ---- conv2 implicit-GEMM MFMA: M=256 pix, N=64 oc, K=288; A fp16-hi, W hi/lo ----
__global__ __launch_bounds__(256) void conv2m_k(const unsigned short* __restrict__ c1h,
                                                const unsigned short* __restrict__ W2h,
                                                const unsigned short* __restrict__ W2l,
                                                const float* __restrict__ bias,
                                                unsigned short* __restrict__ c2h) {
  __shared__ __align__(16) unsigned short sH[32768];
  int bt = blockIdx.x, tid = threadIdx.x;
  {
    const uint4* gh = (const uint4*)(c1h + (size_t)bt*32768);
    for (int i = tid; i < 4096; i += 256) ((uint4*)sH)[i] = gh[i];
  }
  __syncthreads();
  int lane = tid & 63, w = tid >> 6, g = lane >> 4, c = lane & 15;
  f32x4 acc[4][4] = {};
  const uint4 z4 = make_uint4(0,0,0,0);
  #pragma unroll
  for (int pos = 0; pos < 9; ++pos) {
    const int kh = pos / 3, kw = pos % 3;
    HU Ah[4];
    #pragma unroll
    for (int m = 0; m < 4; ++m) {
      int pix = w*64 + m*16 + c;
      int ho = pix >> 4, wo = pix & 15;
      int hi = 2*ho - 1 + kh, wi = 2*wo - 1 + kw;
      bool ok = (hi >= 0) & (wi >= 0);
      int hic = ok ? hi : 0, wic = ok ? wi : 0;
      int a = (((g*32 + hic)*2 + (wic & 1))*16 + (wic >> 1))*8;
      uint4 vh = *(const uint4*)&sH[a];
      Ah[m].q = ok ? vh : z4;
    }
    HU Bh[4], Bl[4];
    #pragma unroll
    for (int n = 0; n < 4; ++n) {
      int off = (n*16 + c)*288 + pos*32 + g*8;
      Bh[n].q = *(const uint4*)(W2h + off);
      Bl[n].q = *(const uint4*)(W2l + off);
    }
    #pragma unroll
    for (int m = 0; m < 4; ++m)
      #pragma unroll
      for (int n = 0; n < 4; ++n) {
        acc[m][n] = MFMAH(Ah[m].v, Bh[n].v, acc[m][n]);
        acc[m][n] = MFMAH(Ah[m].v, Bl[n].v, acc[m][n]);
      }
  }
  #pragma unroll
  for (int n = 0; n < 4; ++n) {
    int oc = n*16 + c;
    float bv = bias[oc];
    int ks3 = oc >> 3, il = oc & 7;
    #pragma unroll
    for (int m = 0; m < 4; ++m) {
      #pragma unroll
      for (int r = 0; r < 4; ++r) {
        int pix = w*64 + m*16 + 4*g + r;
        int ho = pix >> 4, wo = pix & 15;
        float v = fmaxf(acc[m][n][r] + bv, 0.f);
        size_t dst = (size_t)bt*16384 + ((((ks3*16 + ho)*2 + (wo&1))*8 + (wo>>1)))*8 + il;
        c2h[dst] = h16hi(v);
      }
    }
  }
}

// ---- conv3+embed fused: conv3 MFMA -> feats fp16 LDS -> embed MFMA -> node fp32 ----
__global__ __launch_bounds__(256) void conv3e_k(const unsigned short* __restrict__ c2h,
                                                const unsigned short* __restrict__ W3h,
                                                const unsigned short* __restrict__ W3l,
                                                const float* __restrict__ bias,
                                                const unsigned short* __restrict__ WeTh,
                                                const unsigned short* __restrict__ WeTl,
                                                const float* __restrict__ be,
                                                float* __restrict__ node) {
  __shared__ __align__(16) unsigned short sH[16384];
  __shared__ __align__(16) unsigned short sF[64*136];
  int bt = blockIdx.x, tid = threadIdx.x;
  {
    const uint4* gh = (const uint4*)(c2h + (size_t)bt*16384);
    for (int i = tid; i < 2048; i += 256) ((uint4*)sH)[i] = gh[i];
  }
  __syncthreads();
  int lane = tid & 63, w = tid >> 6, g = lane >> 4, c = lane & 15;
  f32x4 acc[8] = {};
  const uint4 z4 = make_uint4(0,0,0,0);
  int pix = w*16 + c;
  int ho = pix >> 3, wo = pix & 7;
  #pragma unroll
  for (int pos = 0; pos < 9; ++pos) {
    const int kh = pos / 3, kw = pos % 3;
    int hi = 2*ho - 1 + kh, wi = 2*wo - 1 + kw;
    bool ok = (hi >= 0) & (wi >= 0);
    int hic = ok ? hi : 0, wic = ok ? wi : 0;
    #pragma unroll
    for (int ih = 0; ih < 2; ++ih) {
      int icg = ih*4 + g;
      int a = ((((icg*16 + hic)*2 + (wic & 1))*8 + (wic >> 1)))*8;
      HU Ah;
      uint4 vh = *(const uint4*)&sH[a];
      Ah.q = ok ? vh : z4;
      #pragma unroll
      for (int n = 0; n < 8; ++n) {
        int off = (n*16 + c)*576 + pos*64 + ih*32 + g*8;
        HU Bh, Bl;
        Bh.q = *(const uint4*)(W3h + off);
        Bl.q = *(const uint4*)(W3l + off);
        acc[n] = MFMAH(Ah.v, Bh.v, acc[n]);
        acc[n] = MFMAH(Ah.v, Bl.v, acc[n]);
      }
    }
  }
  #pragma unroll
  for (int n = 0; n < 8; ++n) {
    int oc = n*16 + c;
    float bv = bias[oc];
    #pragma unroll
    for (int r = 0; r < 4; ++r) {
      int po = w*16 + 4*g + r;
      sF[po*136 + oc] = h16hi(fmaxf(acc[n][r] + bv, 0.f));
    }
  }
  __syncthreads();
  f32x4 eacc[4] = {{0.f,0.f,0.f,0.f},{0.f,0.f,0.f,0.f},{0.f,0.f,0.f,0.f},{0.f,0.f,0.f,0.f}};
  #pragma unroll
  for (int kt = 0; kt < 4; ++kt) {
    HU Af;
    Af.q = *(const uint4*)&sF[(w*16 + c)*136 + kt*32 + g*8];
    #pragma unroll
    for (int n = 0; n < 4; ++n) {
      int off = (n*16 + c)*128 + kt*32 + g*8;
      HU Bh, Bl;
      Bh.q = *(const uint4*)(WeTh + off);
      Bl.q = *(const uint4*)(WeTl + off);
      eacc[n] = MFMAH(Af.v, Bh.v, eacc[n]);
      eacc[n] = MFMAH(Af.v, Bl.v, eacc[n]);
    }
  }
  #pragma unroll
  for (int n = 0; n < 4; ++n) {
    int e = n*16 + c;
    float bev = be[e];
    #pragma unroll
    for (int r = 0; r < 4; ++r) {
      int po = w*16 + 4*g + r;
      node[(size_t)bt*4096 + po*64 + e] = eacc[n][r] + bev;
    }
  }
}

#define MFMA(a, bb, cc) __builtin_amdgcn_mfma_f32_16x16x32_bf16((a), (bb), (cc), 0, 0, 0)

// ---- prep via MFMA hi/lo bf16: A2 = A@A; gx = x@Wx0 + A@(x@Wx1) + A2@(x@Wx2) ----
// gx is exported TRANSPOSED [e][n] so seq2 reads contiguous float4 per thread.
__global__ __launch_bounds__(512) void prepm_k(const float* __restrict__ adj,
                                               const float* __restrict__ node,
                                               const unsigned short* __restrict__ WxTh,
                                               const unsigned short* __restrict__ WxTl,
                                               unsigned short* __restrict__ Abf,
                                               unsigned short* __restrict__ A2bf,
                                               float* __restrict__ gxg) {
  __shared__ __align__(16) unsigned short sAh[64*PS], sAl[64*PS];
  __shared__ __align__(16) unsigned short sXh[64*PS], sXl[64*PS];
  __shared__ __align__(16) unsigned short sNh[64*PS], sNl[64*PS];
  __shared__ __align__(16) unsigned short sZh[64*PS], sZl[64*PS];
  int bt = blockIdx.x, tid = threadIdx.x;
  int lane = tid & 63, w = tid >> 6, g = lane >> 4, c = lane & 15;
  int mt = w & 3, nt0 = (w >> 2) * 2;
  int mrow = mt*16 + 4*g;
  for (int i = tid; i < 1024; i += 512) {
    int r = i >> 4, c0 = (i & 15) * 4;
    float4 av = ((const float4*)(adj + (size_t)bt*4096))[i];
    float4 nv = ((const float4*)(node + (size_t)bt*4096))[i];
    float aa[4] = {av.x, av.y, av.z, av.w};
    float nn[4] = {nv.x, nv.y, nv.z, nv.w};
    ushort4 ah4, al4, nh4, nl4;
    #pragma unroll
    for (int j = 0; j < 4; ++j) {
      unsigned short hi = bf16_rn(aa[j]);
      unsigned short lo = bf16_rn(aa[j] - bf16_tof(hi));
      ((unsigned short*)&ah4)[j] = hi;
      ((unsigned short*)&al4)[j] = lo;
      sXh[(c0+j)*PS + r] = hi;            // AT
      sXl[(c0+j)*PS + r] = lo;
      unsigned short nhi = bf16_rn(nn[j]);
      ((unsigned short*)&nh4)[j] = nhi;
      ((unsigned short*)&nl4)[j] = bf16_rn(nn[j] - bf16_tof(nhi));
    }
    *(ushort4*)&sAh[r*PS + c0] = ah4;
    *(ushort4*)&sAl[r*PS + c0] = al4;
    *(ushort4*)&sNh[r*PS + c0] = nh4;
    *(ushort4*)&sNl[r*PS + c0] = nl4;
    *(ushort4*)&Abf[(size_t)bt*4096 + r*64 + c0] = ah4;
  }
  __syncthreads();
  FU a_h[2], a_l[2], n_h[2], n_l[2];
  #pragma unroll
  for (int kt = 0; kt < 2; ++kt) {
    int ao = (mt*16 + c)*PS + kt*32 + 8*g;
    a_h[kt].q = *(const uint4*)&sAh[ao];
    a_l[kt].q = *(const uint4*)&sAl[ao];
    n_h[kt].q = *(const uint4*)&sNh[ao];
    n_l[kt].q = *(const uint4*)&sNl[ao];
  }
  f32x4 a2f[2] = {{0.f,0.f,0.f,0.f},{0.f,0.f,0.f,0.f}};
  f32x4 zf[2]  = {{0.f,0.f,0.f,0.f},{0.f,0.f,0.f,0.f}};
  #pragma unroll
  for (int tt = 0; tt < 2; ++tt) {
    int e = (nt0+tt)*16 + c;
    #pragma unroll
    for (int kt = 0; kt < 2; ++kt) {
      FU bh, bl;
      int bo = e*PS + kt*32 + 8*g;
      bh.q = *(const uint4*)&sXh[bo];
      bl.q = *(const uint4*)&sXl[bo];
      a2f[tt] = MFMA(a_h[kt].v, bh.v, a2f[tt]);
      a2f[tt] = MFMA(a_l[kt].v, bh.v, a2f[tt]);
      a2f[tt] = MFMA(a_h[kt].v, bl.v, a2f[tt]);
      FU wh, wl;
      int wo = 4096 + e*64 + kt*32 + 8*g;    // Wx1
      wh.q = *(const uint4*)(WxTh + wo);
      wl.q = *(const uint4*)(WxTl + wo);
      zf[tt] = MFMA(n_h[kt].v, wh.v, zf[tt]);
      zf[tt] = MFMA(n_l[kt].v, wh.v, zf[tt]);
      zf[tt] = MFMA(n_h[kt].v, wl.v, zf[tt]);
    }
  }
  __syncthreads();
  #pragma unroll
  for (int tt = 0; tt < 2; ++tt) {
    int e = (nt0+tt)*16 + c;
    ushort4 zh4, zl4;
    #pragma unroll
    for (int r = 0; r < 4; ++r) {
      float va = a2f[tt][r];
      unsigned short ahi = bf16_rn(va);
      sXh[(mrow+r)*PS + e] = ahi;
      sXl[(mrow+r)*PS + e] = bf16_rn(va - bf16_tof(ahi));
      A2bf[(size_t)bt*4096 + (mrow+r)*64 + e] = ahi;
      float vz = zf[tt][r];
      unsigned short zhi = bf16_rn(vz);
      ((unsigned short*)&zh4)[r] = zhi;
      ((unsigned short*)&zl4)[r] = bf16_rn(vz - bf16_tof(zhi));
    }
    *(ushort4*)&sZh[e*PS + mrow] = zh4;
    *(ushort4*)&sZl[e*PS + mrow] = zl4;
  }
  __syncthreads();
  f32x4 gacc[2] = {{0.f,0.f,0.f,0.f},{0.f,0.f,0.f,0.f}};
  #pragma unroll
  for (int tt = 0; tt < 2; ++tt) {
    int e = (nt0+tt)*16 + c;
    zf[tt][0] = 0.f; zf[tt][1] = 0.f; zf[tt][2] = 0.f; zf[tt][3] = 0.f;
    #pragma unroll
    for (int kt = 0; kt < 2; ++kt) {
      FU bh, bl;
      int bo = e*PS + kt*32 + 8*g;
      bh.q = *(const uint4*)&sZh[bo];
      bl.q = *(const uint4*)&sZl[bo];
      gacc[tt] = MFMA(a_h[kt].v, bh.v, gacc[tt]);
      gacc[tt] = MFMA(a_l[kt].v, bh.v, gacc[tt]);
      gacc[tt] = MFMA(a_h[kt].v, bl.v, gacc[tt]);
      FU wh, wl;
      int w0 = e*64 + kt*32 + 8*g;           // Wx0
      wh.q = *(const uint4*)(WxTh + w0);
      wl.q = *(const uint4*)(WxTl + w0);
      gacc[tt] = MFMA(n_h[kt].v, wh.v, gacc[tt]);
      gacc[tt] = MFMA(n_l[kt].v, wh.v, gacc[tt]);
      gacc[tt] = MFMA(n_h[kt].v, wl.v, gacc[tt]);
      int w2 = 8192 + e*64 + kt*32 + 8*g;    // Wx2
      wh.q = *(const uint4*)(WxTh + w2);
      wl.q = *(const uint4*)(WxTl + w2);
      zf[tt] = MFMA(n_h[kt].v, wh.v, zf[tt]);
      zf[tt] = MFMA(n_l[kt].v, wh.v, zf[tt]);
      zf[tt] = MFMA(n_h[kt].v, wl.v, zf[tt]);
    }
  }
  __syncthreads();
  #pragma unroll
  for (int tt = 0; tt < 2; ++tt) {
    int e = (nt0+tt)*16 + c;
    ushort4 zh4, zl4;
    #pragma unroll
    for (int r = 0; r < 4; ++r) {
      float vz = zf[tt][r];
      unsigned short zhi = bf16_rn(vz);
      ((unsigned short*)&zh4)[r] = zhi;
      ((unsigned short*)&zl4)[r] = bf16_rn(vz - bf16_tof(zhi));
    }
    *(ushort4*)&sZh[e*PS + mrow] = zh4;
    *(ushort4*)&sZl[e*PS + mrow] = zl4;
  }
  __syncthreads();
  FU p_h[2], p_l[2];
  #pragma unroll
  for (int kt = 0; kt < 2; ++kt) {
    int po = (mt*16 + c)*PS + kt*32 + 8*g;
    p_h[kt].q = *(const uint4*)&sXh[po];
    p_l[kt].q = *(const uint4*)&sXl[po];
  }
  #pragma unroll
  for (int tt = 0; tt < 2; ++tt) {
    int e = (nt0+tt)*16 + c;
    #pragma unroll
    for (int kt = 0; kt < 2; ++kt) {
      FU bh, bl;
      int bo = e*PS + kt*32 + 8*g;
      bh.q = *(const uint4*)&sZh[bo];
      bl.q = *(const uint4*)&sZl[bo];
      gacc[tt] = MFMA(p_h[kt].v, bh.v, gacc[tt]);
      gacc[tt] = MFMA(p_l[kt].v, bh.v, gacc[tt]);
      gacc[tt] = MFMA(p_h[kt].v, bl.v, gacc[tt]);
    }
    // transposed export: gx[e][n] -> contiguous float4 per thread
    *(float4*)(gxg + (size_t)bt*4096 + e*64 + mrow) =
        make_float4(gacc[tt][0], gacc[tt][1], gacc[tt][2], gacc[tt][3]);
  }
}

// ---- sequential recurrence via MFMA: one block per batch chain, 16 waves ----
// R12 change: A/A2 fragments loaded DIRECT from global (L2-resident) each step;
// LDS staging double-buffer removed. gx read as contiguous float4 (transposed).
__global__ __launch_bounds__(1024, 4) void seq2_k(
    const unsigned short* __restrict__ Abf, const unsigned short* __restrict__ A2bf,
    const float* __restrict__ gxg, const float* __restrict__ h0,
    const unsigned short* __restrict__ WTh, const unsigned short* __restrict__ WTl,
    const float* __restrict__ bg, const float* __restrict__ tau, const float* __restrict__ Apv,
    float* __restrict__ mout, float* __restrict__ out) {
  __shared__ unsigned short sHh[64*72];
  __shared__ unsigned short sZ1[64*72], sZ2[64*72];
  __shared__ float sPart[64*17];
  int b = blockIdx.x, tid = threadIdx.x;
  int lane = tid & 63, w = tid >> 6, g = lane >> 4, c = lane & 15;
  int mt = w & 3, nt = w >> 2;
  int e = nt*16 + c;
  int mrow = mt*16 + 4*g;
  float itau = 1.f/tau[e], apv = Apv[e], bgv = bg[e];
  FU wf[3][2][2];
  #pragma unroll
  for (int k3 = 0; k3 < 3; ++k3)
    #pragma unroll
    for (int kt = 0; kt < 2; ++kt) {
      int off = k3*4096 + e*64 + kt*32 + 8*g;
      wf[k3][kt][0].q = *(const uint4*)(WTh + off);
      wf[k3][kt][1].q = *(const uint4*)(WTl + off);
    }
  float hm[4];
  #pragma unroll
  for (int r = 0; r < 4; ++r) hm[r] = h0[(size_t)b*4096 + (mrow+r)*64 + e];
  #pragma unroll
  for (int r = 0; r < 4; ++r) sHh[(mrow+r)*72 + e] = bfu(hm[r]);
  int arow_off = (mt*16 + c)*64 + 8*g;     // A-frag base within a bt tile
  __syncthreads();
  #pragma unroll 1
  for (int t = 0; t < 64; ++t) {
    size_t bt = (size_t)b*64 + t;
    // direct global fragment loads (L2-resident), issued early
    FU aA[2], aA2[2];
    {
      const unsigned short* Ab  = Abf  + bt*4096 + arow_off;
      const unsigned short* A2b = A2bf + bt*4096 + arow_off;
      #pragma unroll
      for (int kt = 0; kt < 2; ++kt) {
        aA[kt].q  = *(const uint4*)(Ab  + kt*32);
        aA2[kt].q = *(const uint4*)(A2b + kt*32);
      }
    }
    float4 gxv = *(const float4*)(gxg + bt*4096 + e*64 + mrow);
    // ---- z-phase: z1 = h@Wh1, z2 = h@Wh2 ----
    FU ha[2];
    #pragma unroll
    for (int kt = 0; kt < 2; ++kt)
      ha[kt].q = *(const uint4*)&sHh[(mt*16 + c)*72 + kt*32 + 8*g];
    f32x4 a1 = {0.f,0.f,0.f,0.f}, a2 = {0.f,0.f,0.f,0.f};
    #pragma unroll
    for (int kt = 0; kt < 2; ++kt) {
      a1 = MFMA(ha[kt].v, wf[1][kt][0].v, a1);
      a1 = MFMA(ha[kt].v, wf[1][kt][1].v, a1);
      a2 = MFMA(ha[kt].v, wf[2][kt][0].v, a2);
      a2 = MFMA(ha[kt].v, wf[2][kt][1].v, a2);
    }
    {
      ushort4 o1, o2;
      o1.x = bfu(a1[0]); o1.y = bfu(a1[1]); o1.z = bfu(a1[2]); o1.w = bfu(a1[3]);
      o2.x = bfu(a2[0]); o2.y = bfu(a2[1]); o2.z = bfu(a2[2]); o2.w = bfu(a2[3]);
      *(ushort4*)&sZ1[e*72 + mrow] = o1;
      *(ushort4*)&sZ2[e*72 + mrow] = o2;
    }
    __syncthreads();   // B1: sZ ready; sHh reads done
    // ---- gc-phase: gc = h@Wh0 + A@z1 + A2@z2 + gx + bg ----
    f32x4 acc = {0.f,0.f,0.f,0.f};
    #pragma unroll
    for (int kt = 0; kt < 2; ++kt) {
      FU z1f, z2f;
      z1f.q = *(const uint4*)&sZ1[e*72 + kt*32 + 8*g];
      z2f.q = *(const uint4*)&sZ2[e*72 + kt*32 + 8*g];
      acc = MFMA(ha[kt].v, wf[0][kt][0].v, acc);
      acc = MFMA(ha[kt].v, wf[0][kt][1].v, acc);
      acc = MFMA(aA[kt].v,  z1f.v, acc);
      acc = MFMA(aA2[kt].v, z2f.v, acc);
    }
    // h update + write-back + mean partials
    float gxa[4] = {gxv.x, gxv.y, gxv.z, gxv.w};
    float ps = 0.f;
    #pragma unroll
    for (int r = 0; r < 4; ++r) {
      float gc = acc[r] + gxa[r] + bgv;
      float f = tanh_f(gc);
      float hn = hm[r] + DT_C * (-(itau + f) * hm[r] + f * apv);
      hm[r] = hn;
      ps += hn;
      sHh[(mrow+r)*72 + e] = bfu(hn);
    }
    sPart[e*17 + mt*4 + g] = ps;
    __syncthreads();   // B2: h/sPart visible; sZ consumed
    if (lane < 4) {
      int ee = w*4 + lane;
      float s = 0.f;
      #pragma unroll
      for (int j = 0; j < 16; ++j) s += sPart[ee*17 + j];
      mout[bt*64 + ee] = s * (1.0f / 64.0f);
    }
  }
  #pragma unroll
  for (int r = 0; r < 4; ++r)
    out[512 + (size_t)b*4096 + (mrow+r)*64 + e] = hm[r];
}

// ---- decoder MLP for all (b,t) in parallel ----
__global__ __launch_bounds__(128) void dec_k(const float* __restrict__ mout,
                                             const float* __restrict__ Wd1, const float* __restrict__ bd1,
                                             const float* __restrict__ Wd2, const float* __restrict__ bd2,
                                             const float* __restrict__ Wd3, const float* __restrict__ bd3,
                                             float* __restrict__ out) {
  __shared__ float sm[64], sd1[128], sd2[64];
  int bt = blockIdx.x, tid = threadIdx.x;
  if (tid < 64) sm[tid] = mout[(size_t)bt*64 + tid];
  __syncthreads();
  {
    float a = bd1[tid];
    #pragma unroll 8
    for (int e = 0; e < 64; ++e) a += sm[e] * Wd1[e*128 + tid];
    sd1[tid] = fmaxf(a, 0.f);
  }
  __syncthreads();
  if (tid < 64) {
    float a = bd2[tid];
    #pragma unroll 8
    for (int i = 0; i < 128; ++i) a += sd1[i] * Wd2[i*64 + tid];
    sd2[tid] = fmaxf(a, 0.f);
  }
  __syncthreads();
  if (tid < 64) {
    float p = sd2[tid] * Wd3[tid];
    #pragma unroll
    for (int off = 32; off > 0; off >>= 1) p += __shfl_down(p, off, 64);
    if (tid == 0) out[bt] = p + bd3[0];
  }
}

extern "C" void kernel_launch(void* const* d_in, const int* in_sizes, int n_in,
                              void* d_out, int out_size, void* d_ws, size_t ws_size,
                              hipStream_t stream) {
  const float* frames = (const float*)d_in[0];
  const float* adj    = (const float*)d_in[1];
  const float* h0     = (const float*)d_in[2];
  const float* Wc1 = (const float*)d_in[3];  const float* bc1 = (const float*)d_in[4];
  const float* Wc2 = (const float*)d_in[5];  const float* bc2 = (const float*)d_in[6];
  const float* Wc3 = (const float*)d_in[7];  const float* bc3 = (const float*)d_in[8];
  const float* We  = (const float*)d_in[9];  const float* be  = (const float*)d_in[10];
  const float* Wh  = (const float*)d_in[11]; const float* Wx  = (const float*)d_in[12];
  const float* bg  = (const float*)d_in[13]; const float* tau = (const float*)d_in[14];
  const float* Ap  = (const float*)d_in[15];
  const float* Wd1 = (const float*)d_in[16]; const float* bd1 = (const float*)d_in[17];
  const float* Wd2 = (const float*)d_in[18]; const float* bd2 = (const float*)d_in[19];
  const float* Wd3 = (const float*)d_in[20]; const float* bd3 = (const float*)d_in[21];

  float* ws = (float*)d_ws;
  // Workspace map (float offsets; validated R5-R12).
  unsigned short* c1h = (unsigned short*)(ws);
  unsigned short* c2h = (unsigned short*)(ws + 16777216);
  unsigned short* W2h = (unsigned short*)(ws + 20971520);
  unsigned short* W2l = (unsigned short*)(ws + 20980736);
  unsigned short* W3h = (unsigned short*)(ws + 20989952);
  unsigned short* W3l = (unsigned short*)(ws + 21026816);
  unsigned short* WTh = (unsigned short*)(ws + 21063680);
  unsigned short* WTl = (unsigned short*)(ws + 21069824);
  unsigned short* WeTh = (unsigned short*)(ws + 21075968);
  unsigned short* WeTl = (unsigned short*)(ws + 21080064);
  unsigned short* WxTh = (unsigned short*)(ws + 21084160);
  unsigned short* WxTl = (unsigned short*)(ws + 21090304);
  unsigned short* W1h  = (unsigned short*)(ws + 21096448);
  unsigned short* W1l  = (unsigned short*)(ws + 21096960);
  float* node = ws + 4194304;
  float* gx   = ws + 6291456;
  unsigned short* Abf  = (unsigned short*)(ws + 8388608);
  unsigned short* A2bf = (unsigned short*)(ws + 9437184);
  float* mo   = ws + 10485760;
  float* out  = (float*)d_out;

  wprep_k <<<492, 256, 0, stream>>>(Wc2, Wc3, Wh, We, Wx, Wc1, W2h, W2l, W3h, W3l,
                                    WTh, WTl, WeTh, WeTl, WxTh, WxTl, W1h, W1l);
  conv1m_k<<<512, 512, 0, stream>>>(frames, W1h, W1l, bc1, c1h);
  conv2m_k<<<512, 256, 0, stream>>>(c1h, W2h, W2l, bc2, c2h);
  conv3e_k<<<512, 256, 0, stream>>>(c2h, W3h, W3l, bc3, WeTh, WeTl, be, node);
  prepm_k <<<512, 512, 0, stream>>>(adj, node, WxTh, WxTl, Abf, A2bf, gx);
  seq2_k  <<<8,  1024, 0, stream>>>(Abf, A2bf, gx, h0, WTh, WTl, bg, tau, Ap, mo, out);
  dec_k   <<<512, 128, 0, stream>>>(mo, Wd1, bd1, Wd2, bd2, Wd3, bd3, out);
}

// Round 14
// 263.484 us; speedup vs baseline: 1.3199x; 1.3199x over previous
//
#include <hip/hip_runtime.h>
#include <hip/hip_bf16.h>

#define DT_C 0.1f
#define PS 72            // bf16 plane row stride (halves)

typedef short bfrag __attribute__((ext_vector_type(8)));     // 8 bf16
typedef _Float16 hfrag __attribute__((ext_vector_type(8)));  // 8 fp16
typedef float f32x4 __attribute__((ext_vector_type(4)));

union FU { bfrag v; unsigned short s[8]; uint4 q; };
union HU { hfrag v; unsigned short s[8]; uint4 q; };

__device__ __forceinline__ unsigned short bf16_rn(float x) {
  union { float f; unsigned u; } v; v.f = x;
  unsigned r = v.u + 0x7fffu + ((v.u >> 16) & 1u);
  return (unsigned short)(r >> 16);
}
__device__ __forceinline__ float bf16_tof(unsigned short h) {
  union { unsigned u; float f; } v; v.u = ((unsigned)h) << 16; return v.f;
}
__device__ __forceinline__ unsigned short bfu(float x) {
  union { __hip_bfloat16 b; unsigned short u; } cv;
  cv.b = __float2bfloat16(x);
  return cv.u;
}
__device__ __forceinline__ float tanh_f(float x) {
  return 1.0f - 2.0f / (__expf(2.0f * x) + 1.0f);
}
__device__ __forceinline__ void h16split(float v, unsigned short& hu, unsigned short& lu) {
  union { _Float16 h; unsigned short u; } a, b;
  a.h = (_Float16)v;
  b.h = (_Float16)(v - (float)a.h);
  hu = a.u; lu = b.u;
}
__device__ __forceinline__ unsigned short h16hi(float v) {
  union { _Float16 h; unsigned short u; } a; a.h = (_Float16)v; return a.u;
}

// ---- fused weight prep: Wc2->W2 (18432), Wc3->W3 (73728), Wh->WT (12288),
//      We->WeT (8192), Wx->WxT (12288), Wc1->W1T (1024, K padded 27->32) ----
__global__ __launch_bounds__(256) void wprep_k(const float* __restrict__ Wc2,
                                               const float* __restrict__ Wc3,
                                               const float* __restrict__ Wh,
                                               const float* __restrict__ We,
                                               const float* __restrict__ Wx,
                                               const float* __restrict__ Wc1,
                                               unsigned short* __restrict__ W2h,
                                               unsigned short* __restrict__ W2l,
                                               unsigned short* __restrict__ W3h,
                                               unsigned short* __restrict__ W3l,
                                               unsigned short* __restrict__ WTh,
                                               unsigned short* __restrict__ WTl,
                                               unsigned short* __restrict__ WeTh,
                                               unsigned short* __restrict__ WeTl,
                                               unsigned short* __restrict__ WxTh,
                                               unsigned short* __restrict__ WxTl,
                                               unsigned short* __restrict__ W1h,
                                               unsigned short* __restrict__ W1l) {
  int i = blockIdx.x * 256 + threadIdx.x;
  if (i < 18432) {
    int oc = i / 288, rem = i % 288, pos = rem >> 5, ic = rem & 31;
    float v = Wc2[oc*288 + ic*9 + pos];
    h16split(v, W2h[i], W2l[i]);
  } else if (i < 92160) {
    int j = i - 18432;
    int oc = j / 576, rem = j % 576, pos = rem >> 6, ic = rem & 63;
    float v = Wc3[oc*576 + ic*9 + pos];
    h16split(v, W3h[j], W3l[j]);
  } else if (i < 104448) {
    int j = i - 92160;
    int k3 = j >> 12, rem = j & 4095, din = rem >> 6, dout = rem & 63;
    float v = Wh[j];
    unsigned short hi = bf16_rn(v);
    WTh[k3*4096 + dout*64 + din] = hi;
    WTl[k3*4096 + dout*64 + din] = bf16_rn(v - bf16_tof(hi));
  } else if (i < 112640) {
    int j = i - 104448;                    // WeT[e][oc] hi/lo from We[oc][e]
    int e = j >> 7, oc = j & 127;
    float v = We[oc*64 + e];
    h16split(v, WeTh[j], WeTl[j]);
  } else if (i < 124928) {
    int j = i - 112640;                    // WxT[k3][e][din] bf16 hi/lo
    int k3 = j >> 12, rem = j & 4095, e = rem >> 6, din = rem & 63;
    float v = Wx[k3*4096 + din*64 + e];
    unsigned short hi = bf16_rn(v);
    WxTh[j] = hi;
    WxTl[j] = bf16_rn(v - bf16_tof(hi));
  } else if (i < 125952) {
    int j = i - 124928;                    // W1T[oc][k] k=pos*3+ic, pad 27->32
    int oc = j >> 5, k = j & 31;
    float v = 0.f;
    if (k < 27) { int pos = k / 3, ic = k % 3; v = Wc1[oc*27 + ic*9 + pos]; }
    h16split(v, W1h[j], W1l[j]);
  }
}

#define MFMAH(a, bb, cc) __builtin_amdgcn_mfma_f32_16x16x32_f16((a), (bb), (cc), 0, 0, 0)

// ---- conv1 implicit-GEMM MFMA: M=1024 pix, N=32 oc, K=27->32 (k=pos*3+ic) ----
__global__ __launch_bounds__(512) void conv1m_k(const float* __restrict__ frames,
                                                const unsigned short* __restrict__ W1h,
                                                const unsigned short* __restrict__ W1l,
                                                const float* __restrict__ bias,
                                                unsigned short* __restrict__ c1h) {
  __shared__ __align__(16) unsigned short sIn[12288];   // fp16 [3][64][64], 24 KB
  int bt = blockIdx.x, tid = threadIdx.x;
  {
    const float4* src = (const float4*)(frames + (size_t)bt * 12288);
    for (int i = tid; i < 3072; i += 512) {
      float4 v = src[i];
      ushort4 h;
      h.x = h16hi(v.x); h.y = h16hi(v.y); h.z = h16hi(v.z); h.w = h16hi(v.w);
      *(ushort4*)&sIn[i*4] = h;
    }
  }
  __syncthreads();
  int lane = tid & 63, w = tid >> 6, g = lane >> 4, c = lane & 15;
  HU Bh[2], Bl[2];
  #pragma unroll
  for (int n = 0; n < 2; ++n) {
    Bh[n].q = *(const uint4*)(W1h + (n*16 + c)*32 + g*8);
    Bl[n].q = *(const uint4*)(W1l + (n*16 + c)*32 + g*8);
  }
  float bv[2] = {bias[c], bias[16 + c]};
  #pragma unroll 1
  for (int im = 0; im < 8; ++im) {
    int mi = w*8 + im;
    int p = mi*16 + c;
    int ho = p >> 5, wo = p & 31;
    HU Af;
    #pragma unroll
    for (int j = 0; j < 8; ++j) {
      int k = 8*g + j;
      unsigned short v = 0;
      if (k < 27) {
        int pos = k / 3, ic = k % 3;
        int hi = 2*ho - 1 + pos/3, wi = 2*wo - 1 + pos%3;
        v = (hi >= 0 && wi >= 0) ? sIn[ic*4096 + hi*64 + wi] : (unsigned short)0;
      }
      Af.s[j] = v;
    }
    f32x4 acc[2] = {{0.f,0.f,0.f,0.f},{0.f,0.f,0.f,0.f}};
    #pragma unroll
    for (int n = 0; n < 2; ++n) {
      acc[n] = MFMAH(Af.v, Bh[n].v, acc[n]);
      acc[n] = MFMAH(Af.v, Bl[n].v, acc[n]);
    }
    #pragma unroll
    for (int n = 0; n < 2; ++n) {
      int oc = n*16 + c;
      int ks3 = oc >> 3, il = oc & 7;
      #pragma unroll
      for (int r = 0; r < 4; ++r) {
        int po = mi*16 + 4*g + r;
        int ho2 = po >> 5, wo2 = po & 31;
        float v = fmaxf(acc[n][r] + bv[n], 0.f);
        size_t dst = (size_t)bt*32768 + ks3*8192
                   + ((size_t)((ho2*2 + (wo2&1))*16 + (wo2>>1)))*8 + il;
        c1h[dst] = h16hi(v);
      }
    }
  }
}

// ---- conv2 implicit-GEMM MFMA: M=256 pix, N=64 oc, K=288; A fp16-hi, W hi/lo ----
__global__ __launch_bounds__(256) void conv2m_k(const unsigned short* __restrict__ c1h,
                                                const unsigned short* __restrict__ W2h,
                                                const unsigned short* __restrict__ W2l,
                                                const float* __restrict__ bias,
                                                unsigned short* __restrict__ c2h) {
  __shared__ __align__(16) unsigned short sH[32768];
  int bt = blockIdx.x, tid = threadIdx.x;
  {
    const uint4* gh = (const uint4*)(c1h + (size_t)bt*32768);
    for (int i = tid; i < 4096; i += 256) ((uint4*)sH)[i] = gh[i];
  }
  __syncthreads();
  int lane = tid & 63, w = tid >> 6, g = lane >> 4, c = lane & 15;
  f32x4 acc[4][4] = {};
  const uint4 z4 = make_uint4(0,0,0,0);
  #pragma unroll
  for (int pos = 0; pos < 9; ++pos) {
    const int kh = pos / 3, kw = pos % 3;
    HU Ah[4];
    #pragma unroll
    for (int m = 0; m < 4; ++m) {
      int pix = w*64 + m*16 + c;
      int ho = pix >> 4, wo = pix & 15;
      int hi = 2*ho - 1 + kh, wi = 2*wo - 1 + kw;
      bool ok = (hi >= 0) & (wi >= 0);
      int hic = ok ? hi : 0, wic = ok ? wi : 0;
      int a = (((g*32 + hic)*2 + (wic & 1))*16 + (wic >> 1))*8;
      uint4 vh = *(const uint4*)&sH[a];
      Ah[m].q = ok ? vh : z4;
    }
    HU Bh[4], Bl[4];
    #pragma unroll
    for (int n = 0; n < 4; ++n) {
      int off = (n*16 + c)*288 + pos*32 + g*8;
      Bh[n].q = *(const uint4*)(W2h + off);
      Bl[n].q = *(const uint4*)(W2l + off);
    }
    #pragma unroll
    for (int m = 0; m < 4; ++m)
      #pragma unroll
      for (int n = 0; n < 4; ++n) {
        acc[m][n] = MFMAH(Ah[m].v, Bh[n].v, acc[m][n]);
        acc[m][n] = MFMAH(Ah[m].v, Bl[n].v, acc[m][n]);
      }
  }
  #pragma unroll
  for (int n = 0; n < 4; ++n) {
    int oc = n*16 + c;
    float bv = bias[oc];
    int ks3 = oc >> 3, il = oc & 7;
    #pragma unroll
    for (int m = 0; m < 4; ++m) {
      #pragma unroll
      for (int r = 0; r < 4; ++r) {
        int pix = w*64 + m*16 + 4*g + r;
        int ho = pix >> 4, wo = pix & 15;
        float v = fmaxf(acc[m][n][r] + bv, 0.f);
        size_t dst = (size_t)bt*16384 + ((((ks3*16 + ho)*2 + (wo&1))*8 + (wo>>1)))*8 + il;
        c2h[dst] = h16hi(v);
      }
    }
  }
}

// ---- conv3+embed fused: conv3 MFMA -> feats fp16 LDS -> embed MFMA -> node fp32 ----
__global__ __launch_bounds__(256) void conv3e_k(const unsigned short* __restrict__ c2h,
                                                const unsigned short* __restrict__ W3h,
                                                const unsigned short* __restrict__ W3l,
                                                const float* __restrict__ bias,
                                                const unsigned short* __restrict__ WeTh,
                                                const unsigned short* __restrict__ WeTl,
                                                const float* __restrict__ be,
                                                float* __restrict__ node) {
  __shared__ __align__(16) unsigned short sH[16384];
  __shared__ __align__(16) unsigned short sF[64*136];
  int bt = blockIdx.x, tid = threadIdx.x;
  {
    const uint4* gh = (const uint4*)(c2h + (size_t)bt*16384);
    for (int i = tid; i < 2048; i += 256) ((uint4*)sH)[i] = gh[i];
  }
  __syncthreads();
  int lane = tid & 63, w = tid >> 6, g = lane >> 4, c = lane & 15;
  f32x4 acc[8] = {};
  const uint4 z4 = make_uint4(0,0,0,0);
  int pix = w*16 + c;
  int ho = pix >> 3, wo = pix & 7;
  #pragma unroll
  for (int pos = 0; pos < 9; ++pos) {
    const int kh = pos / 3, kw = pos % 3;
    int hi = 2*ho - 1 + kh, wi = 2*wo - 1 + kw;
    bool ok = (hi >= 0) & (wi >= 0);
    int hic = ok ? hi : 0, wic = ok ? wi : 0;
    #pragma unroll
    for (int ih = 0; ih < 2; ++ih) {
      int icg = ih*4 + g;
      int a = ((((icg*16 + hic)*2 + (wic & 1))*8 + (wic >> 1)))*8;
      HU Ah;
      uint4 vh = *(const uint4*)&sH[a];
      Ah.q = ok ? vh : z4;
      #pragma unroll
      for (int n = 0; n < 8; ++n) {
        int off = (n*16 + c)*576 + pos*64 + ih*32 + g*8;
        HU Bh, Bl;
        Bh.q = *(const uint4*)(W3h + off);
        Bl.q = *(const uint4*)(W3l + off);
        acc[n] = MFMAH(Ah.v, Bh.v, acc[n]);
        acc[n] = MFMAH(Ah.v, Bl.v, acc[n]);
      }
    }
  }
  #pragma unroll
  for (int n = 0; n < 8; ++n) {
    int oc = n*16 + c;
    float bv = bias[oc];
    #pragma unroll
    for (int r = 0; r < 4; ++r) {
      int po = w*16 + 4*g + r;
      sF[po*136 + oc] = h16hi(fmaxf(acc[n][r] + bv, 0.f));
    }
  }
  __syncthreads();
  f32x4 eacc[4] = {{0.f,0.f,0.f,0.f},{0.f,0.f,0.f,0.f},{0.f,0.f,0.f,0.f},{0.f,0.f,0.f,0.f}};
  #pragma unroll
  for (int kt = 0; kt < 4; ++kt) {
    HU Af;
    Af.q = *(const uint4*)&sF[(w*16 + c)*136 + kt*32 + g*8];
    #pragma unroll
    for (int n = 0; n < 4; ++n) {
      int off = (n*16 + c)*128 + kt*32 + g*8;
      HU Bh, Bl;
      Bh.q = *(const uint4*)(WeTh + off);
      Bl.q = *(const uint4*)(WeTl + off);
      eacc[n] = MFMAH(Af.v, Bh.v, eacc[n]);
      eacc[n] = MFMAH(Af.v, Bl.v, eacc[n]);
    }
  }
  #pragma unroll
  for (int n = 0; n < 4; ++n) {
    int e = n*16 + c;
    float bev = be[e];
    #pragma unroll
    for (int r = 0; r < 4; ++r) {
      int po = w*16 + 4*g + r;
      node[(size_t)bt*4096 + po*64 + e] = eacc[n][r] + bev;
    }
  }
}

#define MFMA(a, bb, cc) __builtin_amdgcn_mfma_f32_16x16x32_bf16((a), (bb), (cc), 0, 0, 0)

// ---- prep via MFMA hi/lo bf16: A2 = A@A; gx = x@Wx0 + A@(x@Wx1) + A2@(x@Wx2) ----
// gx exported TRANSPOSED [e][n] so seq2 reads one contiguous float4 per thread.
__global__ __launch_bounds__(512) void prepm_k(const float* __restrict__ adj,
                                               const float* __restrict__ node,
                                               const unsigned short* __restrict__ WxTh,
                                               const unsigned short* __restrict__ WxTl,
                                               unsigned short* __restrict__ Abf,
                                               unsigned short* __restrict__ A2bf,
                                               float* __restrict__ gxg) {
  __shared__ __align__(16) unsigned short sAh[64*PS], sAl[64*PS];
  __shared__ __align__(16) unsigned short sXh[64*PS], sXl[64*PS];
  __shared__ __align__(16) unsigned short sNh[64*PS], sNl[64*PS];
  __shared__ __align__(16) unsigned short sZh[64*PS], sZl[64*PS];
  int bt = blockIdx.x, tid = threadIdx.x;
  int lane = tid & 63, w = tid >> 6, g = lane >> 4, c = lane & 15;
  int mt = w & 3, nt0 = (w >> 2) * 2;
  int mrow = mt*16 + 4*g;
  for (int i = tid; i < 1024; i += 512) {
    int r = i >> 4, c0 = (i & 15) * 4;
    float4 av = ((const float4*)(adj + (size_t)bt*4096))[i];
    float4 nv = ((const float4*)(node + (size_t)bt*4096))[i];
    float aa[4] = {av.x, av.y, av.z, av.w};
    float nn[4] = {nv.x, nv.y, nv.z, nv.w};
    ushort4 ah4, al4, nh4, nl4;
    #pragma unroll
    for (int j = 0; j < 4; ++j) {
      unsigned short hi = bf16_rn(aa[j]);
      unsigned short lo = bf16_rn(aa[j] - bf16_tof(hi));
      ((unsigned short*)&ah4)[j] = hi;
      ((unsigned short*)&al4)[j] = lo;
      sXh[(c0+j)*PS + r] = hi;            // AT
      sXl[(c0+j)*PS + r] = lo;
      unsigned short nhi = bf16_rn(nn[j]);
      ((unsigned short*)&nh4)[j] = nhi;
      ((unsigned short*)&nl4)[j] = bf16_rn(nn[j] - bf16_tof(nhi));
    }
    *(ushort4*)&sAh[r*PS + c0] = ah4;
    *(ushort4*)&sAl[r*PS + c0] = al4;
    *(ushort4*)&sNh[r*PS + c0] = nh4;
    *(ushort4*)&sNl[r*PS + c0] = nl4;
    *(ushort4*)&Abf[(size_t)bt*4096 + r*64 + c0] = ah4;
  }
  __syncthreads();
  FU a_h[2], a_l[2], n_h[2], n_l[2];
  #pragma unroll
  for (int kt = 0; kt < 2; ++kt) {
    int ao = (mt*16 + c)*PS + kt*32 + 8*g;
    a_h[kt].q = *(const uint4*)&sAh[ao];
    a_l[kt].q = *(const uint4*)&sAl[ao];
    n_h[kt].q = *(const uint4*)&sNh[ao];
    n_l[kt].q = *(const uint4*)&sNl[ao];
  }
  f32x4 a2f[2] = {{0.f,0.f,0.f,0.f},{0.f,0.f,0.f,0.f}};
  f32x4 zf[2]  = {{0.f,0.f,0.f,0.f},{0.f,0.f,0.f,0.f}};
  #pragma unroll
  for (int tt = 0; tt < 2; ++tt) {
    int e = (nt0+tt)*16 + c;
    #pragma unroll
    for (int kt = 0; kt < 2; ++kt) {
      FU bh, bl;
      int bo = e*PS + kt*32 + 8*g;
      bh.q = *(const uint4*)&sXh[bo];
      bl.q = *(const uint4*)&sXl[bo];
      a2f[tt] = MFMA(a_h[kt].v, bh.v, a2f[tt]);
      a2f[tt] = MFMA(a_l[kt].v, bh.v, a2f[tt]);
      a2f[tt] = MFMA(a_h[kt].v, bl.v, a2f[tt]);
      FU wh, wl;
      int wo = 4096 + e*64 + kt*32 + 8*g;    // Wx1
      wh.q = *(const uint4*)(WxTh + wo);
      wl.q = *(const uint4*)(WxTl + wo);
      zf[tt] = MFMA(n_h[kt].v, wh.v, zf[tt]);
      zf[tt] = MFMA(n_l[kt].v, wh.v, zf[tt]);
      zf[tt] = MFMA(n_h[kt].v, wl.v, zf[tt]);
    }
  }
  __syncthreads();
  #pragma unroll
  for (int tt = 0; tt < 2; ++tt) {
    int e = (nt0+tt)*16 + c;
    ushort4 zh4, zl4;
    #pragma unroll
    for (int r = 0; r < 4; ++r) {
      float va = a2f[tt][r];
      unsigned short ahi = bf16_rn(va);
      sXh[(mrow+r)*PS + e] = ahi;
      sXl[(mrow+r)*PS + e] = bf16_rn(va - bf16_tof(ahi));
      A2bf[(size_t)bt*4096 + (mrow+r)*64 + e] = ahi;
      float vz = zf[tt][r];
      unsigned short zhi = bf16_rn(vz);
      ((unsigned short*)&zh4)[r] = zhi;
      ((unsigned short*)&zl4)[r] = bf16_rn(vz - bf16_tof(zhi));
    }
    *(ushort4*)&sZh[e*PS + mrow] = zh4;
    *(ushort4*)&sZl[e*PS + mrow] = zl4;
  }
  __syncthreads();
  f32x4 gacc[2] = {{0.f,0.f,0.f,0.f},{0.f,0.f,0.f,0.f}};
  #pragma unroll
  for (int tt = 0; tt < 2; ++tt) {
    int e = (nt0+tt)*16 + c;
    zf[tt][0] = 0.f; zf[tt][1] = 0.f; zf[tt][2] = 0.f; zf[tt][3] = 0.f;
    #pragma unroll
    for (int kt = 0; kt < 2; ++kt) {
      FU bh, bl;
      int bo = e*PS + kt*32 + 8*g;
      bh.q = *(const uint4*)&sZh[bo];
      bl.q = *(const uint4*)&sZl[bo];
      gacc[tt] = MFMA(a_h[kt].v, bh.v, gacc[tt]);
      gacc[tt] = MFMA(a_l[kt].v, bh.v, gacc[tt]);
      gacc[tt] = MFMA(a_h[kt].v, bl.v, gacc[tt]);
      FU wh, wl;
      int w0 = e*64 + kt*32 + 8*g;           // Wx0
      wh.q = *(const uint4*)(WxTh + w0);
      wl.q = *(const uint4*)(WxTl + w0);
      gacc[tt] = MFMA(n_h[kt].v, wh.v, gacc[tt]);
      gacc[tt] = MFMA(n_l[kt].v, wh.v, gacc[tt]);
      gacc[tt] = MFMA(n_h[kt].v, wl.v, gacc[tt]);
      int w2 = 8192 + e*64 + kt*32 + 8*g;    // Wx2
      wh.q = *(const uint4*)(WxTh + w2);
      wl.q = *(const uint4*)(WxTl + w2);
      zf[tt] = MFMA(n_h[kt].v, wh.v, zf[tt]);
      zf[tt] = MFMA(n_l[kt].v, wh.v, zf[tt]);
      zf[tt] = MFMA(n_h[kt].v, wl.v, zf[tt]);
    }
  }
  __syncthreads();
  #pragma unroll
  for (int tt = 0; tt < 2; ++tt) {
    int e = (nt0+tt)*16 + c;
    ushort4 zh4, zl4;
    #pragma unroll
    for (int r = 0; r < 4; ++r) {
      float vz = zf[tt][r];
      unsigned short zhi = bf16_rn(vz);
      ((unsigned short*)&zh4)[r] = zhi;
      ((unsigned short*)&zl4)[r] = bf16_rn(vz - bf16_tof(zhi));
    }
    *(ushort4*)&sZh[e*PS + mrow] = zh4;
    *(ushort4*)&sZl[e*PS + mrow] = zl4;
  }
  __syncthreads();
  FU p_h[2], p_l[2];
  #pragma unroll
  for (int kt = 0; kt < 2; ++kt) {
    int po = (mt*16 + c)*PS + kt*32 + 8*g;
    p_h[kt].q = *(const uint4*)&sXh[po];
    p_l[kt].q = *(const uint4*)&sXl[po];
  }
  #pragma unroll
  for (int tt = 0; tt < 2; ++tt) {
    int e = (nt0+tt)*16 + c;
    #pragma unroll
    for (int kt = 0; kt < 2; ++kt) {
      FU bh, bl;
      int bo = e*PS + kt*32 + 8*g;
      bh.q = *(const uint4*)&sZh[bo];
      bl.q = *(const uint4*)&sZl[bo];
      gacc[tt] = MFMA(p_h[kt].v, bh.v, gacc[tt]);
      gacc[tt] = MFMA(p_l[kt].v, bh.v, gacc[tt]);
      gacc[tt] = MFMA(p_h[kt].v, bl.v, gacc[tt]);
    }
    *(float4*)(gxg + (size_t)bt*4096 + e*64 + mrow) =
        make_float4(gacc[tt][0], gacc[tt][1], gacc[tt][2], gacc[tt][3]);
  }
}

// ---- sequential recurrence via MFMA: one block per batch chain, 16 waves ----
// R9/R12 measured-best form (LDS double-buffer A/A2 staging) + transposed-gx float4 read.
__global__ __launch_bounds__(1024, 4) void seq2_k(
    const unsigned short* __restrict__ Abf, const unsigned short* __restrict__ A2bf,
    const float* __restrict__ gxg, const float* __restrict__ h0,
    const unsigned short* __restrict__ WTh, const unsigned short* __restrict__ WTl,
    const float* __restrict__ bg, const float* __restrict__ tau, const float* __restrict__ Apv,
    float* __restrict__ mout, float* __restrict__ out) {
  __shared__ unsigned short sHh[64*72];
  __shared__ unsigned short sA[2][64*72], sA2[2][64*72];
  __shared__ unsigned short sZ1[64*72], sZ2[64*72];
  __shared__ float sPart[64*17];
  int b = blockIdx.x, tid = threadIdx.x;
  int lane = tid & 63, w = tid >> 6, g = lane >> 4, c = lane & 15;
  int mt = w & 3, nt = w >> 2;
  int e = nt*16 + c;
  int mrow = mt*16 + 4*g;
  float itau = 1.f/tau[e], apv = Apv[e], bgv = bg[e];
  FU wf[3][2][2];
  #pragma unroll
  for (int k3 = 0; k3 < 3; ++k3)
    #pragma unroll
    for (int kt = 0; kt < 2; ++kt) {
      int off = k3*4096 + e*64 + kt*32 + 8*g;
      wf[k3][kt][0].q = *(const uint4*)(WTh + off);
      wf[k3][kt][1].q = *(const uint4*)(WTl + off);
    }
  float hm[4];
  #pragma unroll
  for (int r = 0; r < 4; ++r) hm[r] = h0[(size_t)b*4096 + (mrow+r)*64 + e];
  #pragma unroll
  for (int r = 0; r < 4; ++r) sHh[(mrow+r)*72 + e] = bfu(hm[r]);
  {
    int row = tid >> 4, k0 = (tid & 15) * 4;
    *(uint2*)&sA[0][row*72 + k0]  = *(const uint2*)(Abf  + (size_t)b*64*4096 + tid*4);
    *(uint2*)&sA2[0][row*72 + k0] = *(const uint2*)(A2bf + (size_t)b*64*4096 + tid*4);
  }
  __syncthreads();
  #pragma unroll 1
  for (int t = 0; t < 64; ++t) {
    int cur = t & 1;
    size_t bt = (size_t)b*64 + t;
    int tn = (t < 63) ? t + 1 : t;
    uint2 pa  = *(const uint2*)(Abf  + ((size_t)b*64 + tn)*4096 + tid*4);
    uint2 pa2 = *(const uint2*)(A2bf + ((size_t)b*64 + tn)*4096 + tid*4);
    float4 gxv = *(const float4*)(gxg + bt*4096 + e*64 + mrow);
    FU ha[2];
    #pragma unroll
    for (int kt = 0; kt < 2; ++kt)
      ha[kt].q = *(const uint4*)&sHh[(mt*16 + c)*72 + kt*32 + 8*g];
    f32x4 a1 = {0.f,0.f,0.f,0.f}, a2 = {0.f,0.f,0.f,0.f};
    #pragma unroll
    for (int kt = 0; kt < 2; ++kt) {
      a1 = MFMA(ha[kt].v, wf[1][kt][0].v, a1);
      a1 = MFMA(ha[kt].v, wf[1][kt][1].v, a1);
      a2 = MFMA(ha[kt].v, wf[2][kt][0].v, a2);
      a2 = MFMA(ha[kt].v, wf[2][kt][1].v, a2);
    }
    {
      ushort4 o1, o2;
      o1.x = bfu(a1[0]); o1.y = bfu(a1[1]); o1.z = bfu(a1[2]); o1.w = bfu(a1[3]);
      o2.x = bfu(a2[0]); o2.y = bfu(a2[1]); o2.z = bfu(a2[2]); o2.w = bfu(a2[3]);
      *(ushort4*)&sZ1[e*72 + mrow] = o1;
      *(ushort4*)&sZ2[e*72 + mrow] = o2;
    }
    __syncthreads();   // B1
    f32x4 acc = {0.f,0.f,0.f,0.f};
    #pragma unroll
    for (int kt = 0; kt < 2; ++kt) {
      FU aA, aA2, z1f, z2f;
      int ao = (mt*16 + c)*72 + kt*32 + 8*g;
      aA.q  = *(const uint4*)&sA[cur][ao];
      aA2.q = *(const uint4*)&sA2[cur][ao];
      z1f.q = *(const uint4*)&sZ1[e*72 + kt*32 + 8*g];
      z2f.q = *(const uint4*)&sZ2[e*72 + kt*32 + 8*g];
      acc = MFMA(ha[kt].v, wf[0][kt][0].v, acc);
      acc = MFMA(ha[kt].v, wf[0][kt][1].v, acc);
      acc = MFMA(aA.v,  z1f.v, acc);
      acc = MFMA(aA2.v, z2f.v, acc);
    }
    float gxa[4] = {gxv.x, gxv.y, gxv.z, gxv.w};
    float ps = 0.f;
    #pragma unroll
    for (int r = 0; r < 4; ++r) {
      float gc = acc[r] + gxa[r] + bgv;
      float f = tanh_f(gc);
      float hn = hm[r] + DT_C * (-(itau + f) * hm[r] + f * apv);
      hm[r] = hn;
      ps += hn;
      sHh[(mrow+r)*72 + e] = bfu(hn);
    }
    sPart[e*17 + mt*4 + g] = ps;
    {
      int row = tid >> 4, k0 = (tid & 15) * 4;
      *(uint2*)&sA[cur^1][row*72 + k0]  = pa;
      *(uint2*)&sA2[cur^1][row*72 + k0] = pa2;
    }
    __syncthreads();   // B2
    if (lane < 4) {
      int ee = w*4 + lane;
      float s = 0.f;
      #pragma unroll
      for (int j = 0; j < 16; ++j) s += sPart[ee*17 + j];
      mout[bt*64 + ee] = s * (1.0f / 64.0f);
    }
  }
  #pragma unroll
  for (int r = 0; r < 4; ++r)
    out[512 + (size_t)b*4096 + (mrow+r)*64 + e] = hm[r];
}

// ---- decoder MLP for all (b,t) in parallel ----
__global__ __launch_bounds__(128) void dec_k(const float* __restrict__ mout,
                                             const float* __restrict__ Wd1, const float* __restrict__ bd1,
                                             const float* __restrict__ Wd2, const float* __restrict__ bd2,
                                             const float* __restrict__ Wd3, const float* __restrict__ bd3,
                                             float* __restrict__ out) {
  __shared__ float sm[64], sd1[128], sd2[64];
  int bt = blockIdx.x, tid = threadIdx.x;
  if (tid < 64) sm[tid] = mout[(size_t)bt*64 + tid];
  __syncthreads();
  {
    float a = bd1[tid];
    #pragma unroll 8
    for (int e = 0; e < 64; ++e) a += sm[e] * Wd1[e*128 + tid];
    sd1[tid] = fmaxf(a, 0.f);
  }
  __syncthreads();
  if (tid < 64) {
    float a = bd2[tid];
    #pragma unroll 8
    for (int i = 0; i < 128; ++i) a += sd1[i] * Wd2[i*64 + tid];
    sd2[tid] = fmaxf(a, 0.f);
  }
  __syncthreads();
  if (tid < 64) {
    float p = sd2[tid] * Wd3[tid];
    #pragma unroll
    for (int off = 32; off > 0; off >>= 1) p += __shfl_down(p, off, 64);
    if (tid == 0) out[bt] = p + bd3[0];
  }
}

extern "C" void kernel_launch(void* const* d_in, const int* in_sizes, int n_in,
                              void* d_out, int out_size, void* d_ws, size_t ws_size,
                              hipStream_t stream) {
  const float* frames = (const float*)d_in[0];
  const float* adj    = (const float*)d_in[1];
  const float* h0     = (const float*)d_in[2];
  const float* Wc1 = (const float*)d_in[3];  const float* bc1 = (const float*)d_in[4];
  const float* Wc2 = (const float*)d_in[5];  const float* bc2 = (const float*)d_in[6];
  const float* Wc3 = (const float*)d_in[7];  const float* bc3 = (const float*)d_in[8];
  const float* We  = (const float*)d_in[9];  const float* be  = (const float*)d_in[10];
  const float* Wh  = (const float*)d_in[11]; const float* Wx  = (const float*)d_in[12];
  const float* bg  = (const float*)d_in[13]; const float* tau = (const float*)d_in[14];
  const float* Ap  = (const float*)d_in[15];
  const float* Wd1 = (const float*)d_in[16]; const float* bd1 = (const float*)d_in[17];
  const float* Wd2 = (const float*)d_in[18]; const float* bd2 = (const float*)d_in[19];
  const float* Wd3 = (const float*)d_in[20]; const float* bd3 = (const float*)d_in[21];

  float* ws = (float*)d_ws;
  // Workspace map (float offsets; validated R5-R13).
  unsigned short* c1h = (unsigned short*)(ws);
  unsigned short* c2h = (unsigned short*)(ws + 16777216);
  unsigned short* W2h = (unsigned short*)(ws + 20971520);
  unsigned short* W2l = (unsigned short*)(ws + 20980736);
  unsigned short* W3h = (unsigned short*)(ws + 20989952);
  unsigned short* W3l = (unsigned short*)(ws + 21026816);
  unsigned short* WTh = (unsigned short*)(ws + 21063680);
  unsigned short* WTl = (unsigned short*)(ws + 21069824);
  unsigned short* WeTh = (unsigned short*)(ws + 21075968);
  unsigned short* WeTl = (unsigned short*)(ws + 21080064);
  unsigned short* WxTh = (unsigned short*)(ws + 21084160);
  unsigned short* WxTl = (unsigned short*)(ws + 21090304);
  unsigned short* W1h  = (unsigned short*)(ws + 21096448);
  unsigned short* W1l  = (unsigned short*)(ws + 21096960);
  float* node = ws + 4194304;
  float* gx   = ws + 6291456;
  unsigned short* Abf  = (unsigned short*)(ws + 8388608);
  unsigned short* A2bf = (unsigned short*)(ws + 9437184);
  float* mo   = ws + 10485760;
  float* out  = (float*)d_out;

  wprep_k <<<492, 256, 0, stream>>>(Wc2, Wc3, Wh, We, Wx, Wc1, W2h, W2l, W3h, W3l,
                                    WTh, WTl, WeTh, WeTl, WxTh, WxTl, W1h, W1l);
  conv1m_k<<<512, 512, 0, stream>>>(frames, W1h, W1l, bc1, c1h);
  conv2m_k<<<512, 256, 0, stream>>>(c1h, W2h, W2l, bc2, c2h);
  conv3e_k<<<512, 256, 0, stream>>>(c2h, W3h, W3l, bc3, WeTh, WeTl, be, node);
  prepm_k <<<512, 512, 0, stream>>>(adj, node, WxTh, WxTl, Abf, A2bf, gx);
  seq2_k  <<<8,  1024, 0, stream>>>(Abf, A2bf, gx, h0, WTh, WTl, bg, tau, Ap, mo, out);
  dec_k   <<<512, 128, 0, stream>>>(mo, Wd1, bd1, Wd2, bd2, Wd3, bd3, out);
}

// Round 15
// 263.193 us; speedup vs baseline: 1.3214x; 1.0011x over previous
//
#include <hip/hip_runtime.h>
#include <hip/hip_bf16.h>

#define DT_C 0.1f
#define PS 72            // bf16 plane row stride (halves)

typedef short bfrag __attribute__((ext_vector_type(8)));     // 8 bf16
typedef _Float16 hfrag __attribute__((ext_vector_type(8)));  // 8 fp16
typedef float f32x4 __attribute__((ext_vector_type(4)));

union FU { bfrag v; unsigned short s[8]; uint4 q; };
union HU { hfrag v; unsigned short s[8]; uint4 q; };

__device__ __forceinline__ unsigned short bf16_rn(float x) {
  union { float f; unsigned u; } v; v.f = x;
  unsigned r = v.u + 0x7fffu + ((v.u >> 16) & 1u);
  return (unsigned short)(r >> 16);
}
__device__ __forceinline__ float bf16_tof(unsigned short h) {
  union { unsigned u; float f; } v; v.u = ((unsigned)h) << 16; return v.f;
}
__device__ __forceinline__ unsigned short bfu(float x) {
  union { __hip_bfloat16 b; unsigned short u; } cv;
  cv.b = __float2bfloat16(x);
  return cv.u;
}
__device__ __forceinline__ float tanh_f(float x) {
  return 1.0f - 2.0f / (__expf(2.0f * x) + 1.0f);
}
__device__ __forceinline__ void h16split(float v, unsigned short& hu, unsigned short& lu) {
  union { _Float16 h; unsigned short u; } a, b;
  a.h = (_Float16)v;
  b.h = (_Float16)(v - (float)a.h);
  hu = a.u; lu = b.u;
}
__device__ __forceinline__ unsigned short h16hi(float v) {
  union { _Float16 h; unsigned short u; } a; a.h = (_Float16)v; return a.u;
}

// ---- fused weight prep (unchanged from R14) ----
__global__ __launch_bounds__(256) void wprep_k(const float* __restrict__ Wc2,
                                               const float* __restrict__ Wc3,
                                               const float* __restrict__ Wh,
                                               const float* __restrict__ We,
                                               const float* __restrict__ Wx,
                                               const float* __restrict__ Wc1,
                                               unsigned short* __restrict__ W2h,
                                               unsigned short* __restrict__ W2l,
                                               unsigned short* __restrict__ W3h,
                                               unsigned short* __restrict__ W3l,
                                               unsigned short* __restrict__ WTh,
                                               unsigned short* __restrict__ WTl,
                                               unsigned short* __restrict__ WeTh,
                                               unsigned short* __restrict__ WeTl,
                                               unsigned short* __restrict__ WxTh,
                                               unsigned short* __restrict__ WxTl,
                                               unsigned short* __restrict__ W1h,
                                               unsigned short* __restrict__ W1l) {
  int i = blockIdx.x * 256 + threadIdx.x;
  if (i < 18432) {
    int oc = i / 288, rem = i % 288, pos = rem >> 5, ic = rem & 31;
    float v = Wc2[oc*288 + ic*9 + pos];
    h16split(v, W2h[i], W2l[i]);
  } else if (i < 92160) {
    int j = i - 18432;
    int oc = j / 576, rem = j % 576, pos = rem >> 6, ic = rem & 63;
    float v = Wc3[oc*576 + ic*9 + pos];
    h16split(v, W3h[j], W3l[j]);
  } else if (i < 104448) {
    int j = i - 92160;
    int k3 = j >> 12, rem = j & 4095, din = rem >> 6, dout = rem & 63;
    float v = Wh[j];
    unsigned short hi = bf16_rn(v);
    WTh[k3*4096 + dout*64 + din] = hi;
    WTl[k3*4096 + dout*64 + din] = bf16_rn(v - bf16_tof(hi));
  } else if (i < 112640) {
    int j = i - 104448;                    // WeT[e][oc] hi/lo
    int e = j >> 7, oc = j & 127;
    float v = We[oc*64 + e];
    h16split(v, WeTh[j], WeTl[j]);
  } else if (i < 124928) {
    int j = i - 112640;                    // WxT[k3][e][din] bf16 hi/lo
    int k3 = j >> 12, rem = j & 4095, e = rem >> 6, din = rem & 63;
    float v = Wx[k3*4096 + din*64 + e];
    unsigned short hi = bf16_rn(v);
    WxTh[j] = hi;
    WxTl[j] = bf16_rn(v - bf16_tof(hi));
  } else if (i < 125952) {
    int j = i - 124928;                    // W1T[oc][k] k=pos*3+ic, pad 27->32
    int oc = j >> 5, k = j & 31;
    float v = 0.f;
    if (k < 27) { int pos = k / 3, ic = k % 3; v = Wc1[oc*27 + ic*9 + pos]; }
    h16split(v, W1h[j], W1l[j]);
  }
}

#define MFMAH(a, bb, cc) __builtin_amdgcn_mfma_f32_16x16x32_f16((a), (bb), (cc), 0, 0, 0)

// ---- FUSED conv1+conv2: frames -> (conv1 MFMA, LDS c1) -> conv2 MFMA -> c2h ----
// conv1: M=1024 pix, N=32 oc, K=32; c1 kept in LDS (conv2-staging layout [4][32][2][16][8]).
// conv2: M=256 pix (8 waves x 2 m-tiles), N=64 oc, K=288.
__global__ __launch_bounds__(512) void c12_k(const float* __restrict__ frames,
                                             const unsigned short* __restrict__ W1h,
                                             const unsigned short* __restrict__ W1l,
                                             const float* __restrict__ bc1,
                                             const unsigned short* __restrict__ W2h,
                                             const unsigned short* __restrict__ W2l,
                                             const float* __restrict__ bc2,
                                             unsigned short* __restrict__ c2h) {
  __shared__ __align__(16) unsigned short sIn[12288];   // fp16 [3][64][64], 24 KB
  __shared__ __align__(16) unsigned short sC1[32768];   // c1 fp16, 64 KB
  int bt = blockIdx.x, tid = threadIdx.x;
  {
    const float4* src = (const float4*)(frames + (size_t)bt * 12288);
    for (int i = tid; i < 3072; i += 512) {
      float4 v = src[i];
      ushort4 h;
      h.x = h16hi(v.x); h.y = h16hi(v.y); h.z = h16hi(v.z); h.w = h16hi(v.w);
      *(ushort4*)&sIn[i*4] = h;
    }
  }
  __syncthreads();
  int lane = tid & 63, w = tid >> 6, g = lane >> 4, c = lane & 15;
  const uint4 z4 = make_uint4(0,0,0,0);
  // ---- conv1 part: 8 waves x 8 m-tiles ----
  {
    HU Bh[2], Bl[2];
    #pragma unroll
    for (int n = 0; n < 2; ++n) {
      Bh[n].q = *(const uint4*)(W1h + (n*16 + c)*32 + g*8);
      Bl[n].q = *(const uint4*)(W1l + (n*16 + c)*32 + g*8);
    }
    float bv[2] = {bc1[c], bc1[16 + c]};
    #pragma unroll 1
    for (int im = 0; im < 8; ++im) {
      int mi = w*8 + im;
      int p = mi*16 + c;
      int ho = p >> 5, wo = p & 31;
      HU Af;
      #pragma unroll
      for (int j = 0; j < 8; ++j) {
        int k = 8*g + j;
        unsigned short v = 0;
        if (k < 27) {
          int pos = k / 3, ic = k % 3;
          int hi = 2*ho - 1 + pos/3, wi = 2*wo - 1 + pos%3;
          v = (hi >= 0 && wi >= 0) ? sIn[ic*4096 + hi*64 + wi] : (unsigned short)0;
        }
        Af.s[j] = v;
      }
      f32x4 acc[2] = {{0.f,0.f,0.f,0.f},{0.f,0.f,0.f,0.f}};
      #pragma unroll
      for (int n = 0; n < 2; ++n) {
        acc[n] = MFMAH(Af.v, Bh[n].v, acc[n]);
        acc[n] = MFMAH(Af.v, Bl[n].v, acc[n]);
      }
      #pragma unroll
      for (int n = 0; n < 2; ++n) {
        int oc = n*16 + c;
        int ks3 = oc >> 3, il = oc & 7;
        #pragma unroll
        for (int r = 0; r < 4; ++r) {
          int po = mi*16 + 4*g + r;
          int ho2 = po >> 5, wo2 = po & 31;
          float v = fmaxf(acc[n][r] + bv[n], 0.f);
          sC1[ks3*8192 + ((ho2*2 + (wo2&1))*16 + (wo2>>1))*8 + il] = h16hi(v);
        }
      }
    }
  }
  __syncthreads();
  // ---- conv2 part: 8 waves x 2 m-tiles, N=64, K=288 ----
  f32x4 acc2[2][4] = {};
  #pragma unroll
  for (int pos = 0; pos < 9; ++pos) {
    const int kh = pos / 3, kw = pos % 3;
    HU Ah[2];
    #pragma unroll
    for (int m = 0; m < 2; ++m) {
      int pix = w*32 + m*16 + c;
      int ho = pix >> 4, wo = pix & 15;
      int hi = 2*ho - 1 + kh, wi = 2*wo - 1 + kw;
      bool ok = (hi >= 0) & (wi >= 0);
      int hic = ok ? hi : 0, wic = ok ? wi : 0;
      int a = (((g*32 + hic)*2 + (wic & 1))*16 + (wic >> 1))*8;
      uint4 vh = *(const uint4*)&sC1[a];
      Ah[m].q = ok ? vh : z4;
    }
    HU Bh[4], Bl[4];
    #pragma unroll
    for (int n = 0; n < 4; ++n) {
      int off = (n*16 + c)*288 + pos*32 + g*8;
      Bh[n].q = *(const uint4*)(W2h + off);
      Bl[n].q = *(const uint4*)(W2l + off);
    }
    #pragma unroll
    for (int m = 0; m < 2; ++m)
      #pragma unroll
      for (int n = 0; n < 4; ++n) {
        acc2[m][n] = MFMAH(Ah[m].v, Bh[n].v, acc2[m][n]);
        acc2[m][n] = MFMAH(Ah[m].v, Bl[n].v, acc2[m][n]);
      }
  }
  #pragma unroll
  for (int n = 0; n < 4; ++n) {
    int oc = n*16 + c;
    float bv = bc2[oc];
    int ks3 = oc >> 3, il = oc & 7;
    #pragma unroll
    for (int m = 0; m < 2; ++m) {
      #pragma unroll
      for (int r = 0; r < 4; ++r) {
        int pix = w*32 + m*16 + 4*g + r;
        int ho = pix >> 4, wo = pix & 15;
        float v = fmaxf(acc2[m][n][r] + bv, 0.f);
        size_t dst = (size_t)bt*16384 + ((((ks3*16 + ho)*2 + (wo&1))*8 + (wo>>1)))*8 + il;
        c2h[dst] = h16hi(v);
      }
    }
  }
}

// ---- conv3+embed fused (unchanged from R14) ----
__global__ __launch_bounds__(256) void conv3e_k(const unsigned short* __restrict__ c2h,
                                                const unsigned short* __restrict__ W3h,
                                                const unsigned short* __restrict__ W3l,
                                                const float* __restrict__ bias,
                                                const unsigned short* __restrict__ WeTh,
                                                const unsigned short* __restrict__ WeTl,
                                                const float* __restrict__ be,
                                                float* __restrict__ node) {
  __shared__ __align__(16) unsigned short sH[16384];
  __shared__ __align__(16) unsigned short sF[64*136];
  int bt = blockIdx.x, tid = threadIdx.x;
  {
    const uint4* gh = (const uint4*)(c2h + (size_t)bt*16384);
    for (int i = tid; i < 2048; i += 256) ((uint4*)sH)[i] = gh[i];
  }
  __syncthreads();
  int lane = tid & 63, w = tid >> 6, g = lane >> 4, c = lane & 15;
  f32x4 acc[8] = {};
  const uint4 z4 = make_uint4(0,0,0,0);
  int pix = w*16 + c;
  int ho = pix >> 3, wo = pix & 7;
  #pragma unroll
  for (int pos = 0; pos < 9; ++pos) {
    const int kh = pos / 3, kw = pos % 3;
    int hi = 2*ho - 1 + kh, wi = 2*wo - 1 + kw;
    bool ok = (hi >= 0) & (wi >= 0);
    int hic = ok ? hi : 0, wic = ok ? wi : 0;
    #pragma unroll
    for (int ih = 0; ih < 2; ++ih) {
      int icg = ih*4 + g;
      int a = ((((icg*16 + hic)*2 + (wic & 1))*8 + (wic >> 1)))*8;
      HU Ah;
      uint4 vh = *(const uint4*)&sH[a];
      Ah.q = ok ? vh : z4;
      #pragma unroll
      for (int n = 0; n < 8; ++n) {
        int off = (n*16 + c)*576 + pos*64 + ih*32 + g*8;
        HU Bh, Bl;
        Bh.q = *(const uint4*)(W3h + off);
        Bl.q = *(const uint4*)(W3l + off);
        acc[n] = MFMAH(Ah.v, Bh.v, acc[n]);
        acc[n] = MFMAH(Ah.v, Bl.v, acc[n]);
      }
    }
  }
  #pragma unroll
  for (int n = 0; n < 8; ++n) {
    int oc = n*16 + c;
    float bv = bias[oc];
    #pragma unroll
    for (int r = 0; r < 4; ++r) {
      int po = w*16 + 4*g + r;
      sF[po*136 + oc] = h16hi(fmaxf(acc[n][r] + bv, 0.f));
    }
  }
  __syncthreads();
  f32x4 eacc[4] = {{0.f,0.f,0.f,0.f},{0.f,0.f,0.f,0.f},{0.f,0.f,0.f,0.f},{0.f,0.f,0.f,0.f}};
  #pragma unroll
  for (int kt = 0; kt < 4; ++kt) {
    HU Af;
    Af.q = *(const uint4*)&sF[(w*16 + c)*136 + kt*32 + g*8];
    #pragma unroll
    for (int n = 0; n < 4; ++n) {
      int off = (n*16 + c)*128 + kt*32 + g*8;
      HU Bh, Bl;
      Bh.q = *(const uint4*)(WeTh + off);
      Bl.q = *(const uint4*)(WeTl + off);
      eacc[n] = MFMAH(Af.v, Bh.v, eacc[n]);
      eacc[n] = MFMAH(Af.v, Bl.v, eacc[n]);
    }
  }
  #pragma unroll
  for (int n = 0; n < 4; ++n) {
    int e = n*16 + c;
    float bev = be[e];
    #pragma unroll
    for (int r = 0; r < 4; ++r) {
      int po = w*16 + 4*g + r;
      node[(size_t)bt*4096 + po*64 + e] = eacc[n][r] + bev;
    }
  }
}

#define MFMA(a, bb, cc) __builtin_amdgcn_mfma_f32_16x16x32_bf16((a), (bb), (cc), 0, 0, 0)

// ---- prep via MFMA hi/lo bf16 (unchanged from R14) ----
__global__ __launch_bounds__(512) void prepm_k(const float* __restrict__ adj,
                                               const float* __restrict__ node,
                                               const unsigned short* __restrict__ WxTh,
                                               const unsigned short* __restrict__ WxTl,
                                               unsigned short* __restrict__ Abf,
                                               unsigned short* __restrict__ A2bf,
                                               float* __restrict__ gxg) {
  __shared__ __align__(16) unsigned short sAh[64*PS], sAl[64*PS];
  __shared__ __align__(16) unsigned short sXh[64*PS], sXl[64*PS];
  __shared__ __align__(16) unsigned short sNh[64*PS], sNl[64*PS];
  __shared__ __align__(16) unsigned short sZh[64*PS], sZl[64*PS];
  int bt = blockIdx.x, tid = threadIdx.x;
  int lane = tid & 63, w = tid >> 6, g = lane >> 4, c = lane & 15;
  int mt = w & 3, nt0 = (w >> 2) * 2;
  int mrow = mt*16 + 4*g;
  for (int i = tid; i < 1024; i += 512) {
    int r = i >> 4, c0 = (i & 15) * 4;
    float4 av = ((const float4*)(adj + (size_t)bt*4096))[i];
    float4 nv = ((const float4*)(node + (size_t)bt*4096))[i];
    float aa[4] = {av.x, av.y, av.z, av.w};
    float nn[4] = {nv.x, nv.y, nv.z, nv.w};
    ushort4 ah4, al4, nh4, nl4;
    #pragma unroll
    for (int j = 0; j < 4; ++j) {
      unsigned short hi = bf16_rn(aa[j]);
      unsigned short lo = bf16_rn(aa[j] - bf16_tof(hi));
      ((unsigned short*)&ah4)[j] = hi;
      ((unsigned short*)&al4)[j] = lo;
      sXh[(c0+j)*PS + r] = hi;            // AT
      sXl[(c0+j)*PS + r] = lo;
      unsigned short nhi = bf16_rn(nn[j]);
      ((unsigned short*)&nh4)[j] = nhi;
      ((unsigned short*)&nl4)[j] = bf16_rn(nn[j] - bf16_tof(nhi));
    }
    *(ushort4*)&sAh[r*PS + c0] = ah4;
    *(ushort4*)&sAl[r*PS + c0] = al4;
    *(ushort4*)&sNh[r*PS + c0] = nh4;
    *(ushort4*)&sNl[r*PS + c0] = nl4;
    *(ushort4*)&Abf[(size_t)bt*4096 + r*64 + c0] = ah4;
  }
  __syncthreads();
  FU a_h[2], a_l[2], n_h[2], n_l[2];
  #pragma unroll
  for (int kt = 0; kt < 2; ++kt) {
    int ao = (mt*16 + c)*PS + kt*32 + 8*g;
    a_h[kt].q = *(const uint4*)&sAh[ao];
    a_l[kt].q = *(const uint4*)&sAl[ao];
    n_h[kt].q = *(const uint4*)&sNh[ao];
    n_l[kt].q = *(const uint4*)&sNl[ao];
  }
  f32x4 a2f[2] = {{0.f,0.f,0.f,0.f},{0.f,0.f,0.f,0.f}};
  f32x4 zf[2]  = {{0.f,0.f,0.f,0.f},{0.f,0.f,0.f,0.f}};
  #pragma unroll
  for (int tt = 0; tt < 2; ++tt) {
    int e = (nt0+tt)*16 + c;
    #pragma unroll
    for (int kt = 0; kt < 2; ++kt) {
      FU bh, bl;
      int bo = e*PS + kt*32 + 8*g;
      bh.q = *(const uint4*)&sXh[bo];
      bl.q = *(const uint4*)&sXl[bo];
      a2f[tt] = MFMA(a_h[kt].v, bh.v, a2f[tt]);
      a2f[tt] = MFMA(a_l[kt].v, bh.v, a2f[tt]);
      a2f[tt] = MFMA(a_h[kt].v, bl.v, a2f[tt]);
      FU wh, wl;
      int wo = 4096 + e*64 + kt*32 + 8*g;    // Wx1
      wh.q = *(const uint4*)(WxTh + wo);
      wl.q = *(const uint4*)(WxTl + wo);
      zf[tt] = MFMA(n_h[kt].v, wh.v, zf[tt]);
      zf[tt] = MFMA(n_l[kt].v, wh.v, zf[tt]);
      zf[tt] = MFMA(n_h[kt].v, wl.v, zf[tt]);
    }
  }
  __syncthreads();
  #pragma unroll
  for (int tt = 0; tt < 2; ++tt) {
    int e = (nt0+tt)*16 + c;
    ushort4 zh4, zl4;
    #pragma unroll
    for (int r = 0; r < 4; ++r) {
      float va = a2f[tt][r];
      unsigned short ahi = bf16_rn(va);
      sXh[(mrow+r)*PS + e] = ahi;
      sXl[(mrow+r)*PS + e] = bf16_rn(va - bf16_tof(ahi));
      A2bf[(size_t)bt*4096 + (mrow+r)*64 + e] = ahi;
      float vz = zf[tt][r];
      unsigned short zhi = bf16_rn(vz);
      ((unsigned short*)&zh4)[r] = zhi;
      ((unsigned short*)&zl4)[r] = bf16_rn(vz - bf16_tof(zhi));
    }
    *(ushort4*)&sZh[e*PS + mrow] = zh4;
    *(ushort4*)&sZl[e*PS + mrow] = zl4;
  }
  __syncthreads();
  f32x4 gacc[2] = {{0.f,0.f,0.f,0.f},{0.f,0.f,0.f,0.f}};
  #pragma unroll
  for (int tt = 0; tt < 2; ++tt) {
    int e = (nt0+tt)*16 + c;
    zf[tt][0] = 0.f; zf[tt][1] = 0.f; zf[tt][2] = 0.f; zf[tt][3] = 0.f;
    #pragma unroll
    for (int kt = 0; kt < 2; ++kt) {
      FU bh, bl;
      int bo = e*PS + kt*32 + 8*g;
      bh.q = *(const uint4*)&sZh[bo];
      bl.q = *(const uint4*)&sZl[bo];
      gacc[tt] = MFMA(a_h[kt].v, bh.v, gacc[tt]);
      gacc[tt] = MFMA(a_l[kt].v, bh.v, gacc[tt]);
      gacc[tt] = MFMA(a_h[kt].v, bl.v, gacc[tt]);
      FU wh, wl;
      int w0 = e*64 + kt*32 + 8*g;           // Wx0
      wh.q = *(const uint4*)(WxTh + w0);
      wl.q = *(const uint4*)(WxTl + w0);
      gacc[tt] = MFMA(n_h[kt].v, wh.v, gacc[tt]);
      gacc[tt] = MFMA(n_l[kt].v, wh.v, gacc[tt]);
      gacc[tt] = MFMA(n_h[kt].v, wl.v, gacc[tt]);
      int w2 = 8192 + e*64 + kt*32 + 8*g;    // Wx2
      wh.q = *(const uint4*)(WxTh + w2);
      wl.q = *(const uint4*)(WxTl + w2);
      zf[tt] = MFMA(n_h[kt].v, wh.v, zf[tt]);
      zf[tt] = MFMA(n_l[kt].v, wh.v, zf[tt]);
      zf[tt] = MFMA(n_h[kt].v, wl.v, zf[tt]);
    }
  }
  __syncthreads();
  #pragma unroll
  for (int tt = 0; tt < 2; ++tt) {
    int e = (nt0+tt)*16 + c;
    ushort4 zh4, zl4;
    #pragma unroll
    for (int r = 0; r < 4; ++r) {
      float vz = zf[tt][r];
      unsigned short zhi = bf16_rn(vz);
      ((unsigned short*)&zh4)[r] = zhi;
      ((unsigned short*)&zl4)[r] = bf16_rn(vz - bf16_tof(zhi));
    }
    *(ushort4*)&sZh[e*PS + mrow] = zh4;
    *(ushort4*)&sZl[e*PS + mrow] = zl4;
  }
  __syncthreads();
  FU p_h[2], p_l[2];
  #pragma unroll
  for (int kt = 0; kt < 2; ++kt) {
    int po = (mt*16 + c)*PS + kt*32 + 8*g;
    p_h[kt].q = *(const uint4*)&sXh[po];
    p_l[kt].q = *(const uint4*)&sXl[po];
  }
  #pragma unroll
  for (int tt = 0; tt < 2; ++tt) {
    int e = (nt0+tt)*16 + c;
    #pragma unroll
    for (int kt = 0; kt < 2; ++kt) {
      FU bh, bl;
      int bo = e*PS + kt*32 + 8*g;
      bh.q = *(const uint4*)&sZh[bo];
      bl.q = *(const uint4*)&sZl[bo];
      gacc[tt] = MFMA(p_h[kt].v, bh.v, gacc[tt]);
      gacc[tt] = MFMA(p_l[kt].v, bh.v, gacc[tt]);
      gacc[tt] = MFMA(p_h[kt].v, bl.v, gacc[tt]);
    }
    *(float4*)(gxg + (size_t)bt*4096 + e*64 + mrow) =
        make_float4(gacc[tt][0], gacc[tt][1], gacc[tt][2], gacc[tt][3]);
  }
}

// ---- sequential recurrence via MFMA (R14 measured-best form, unchanged) ----
__global__ __launch_bounds__(1024, 4) void seq2_k(
    const unsigned short* __restrict__ Abf, const unsigned short* __restrict__ A2bf,
    const float* __restrict__ gxg, const float* __restrict__ h0,
    const unsigned short* __restrict__ WTh, const unsigned short* __restrict__ WTl,
    const float* __restrict__ bg, const float* __restrict__ tau, const float* __restrict__ Apv,
    float* __restrict__ mout, float* __restrict__ out) {
  __shared__ unsigned short sHh[64*72];
  __shared__ unsigned short sA[2][64*72], sA2[2][64*72];
  __shared__ unsigned short sZ1[64*72], sZ2[64*72];
  __shared__ float sPart[64*17];
  int b = blockIdx.x, tid = threadIdx.x;
  int lane = tid & 63, w = tid >> 6, g = lane >> 4, c = lane & 15;
  int mt = w & 3, nt = w >> 2;
  int e = nt*16 + c;
  int mrow = mt*16 + 4*g;
  float itau = 1.f/tau[e], apv = Apv[e], bgv = bg[e];
  FU wf[3][2][2];
  #pragma unroll
  for (int k3 = 0; k3 < 3; ++k3)
    #pragma unroll
    for (int kt = 0; kt < 2; ++kt) {
      int off = k3*4096 + e*64 + kt*32 + 8*g;
      wf[k3][kt][0].q = *(const uint4*)(WTh + off);
      wf[k3][kt][1].q = *(const uint4*)(WTl + off);
    }
  float hm[4];
  #pragma unroll
  for (int r = 0; r < 4; ++r) hm[r] = h0[(size_t)b*4096 + (mrow+r)*64 + e];
  #pragma unroll
  for (int r = 0; r < 4; ++r) sHh[(mrow+r)*72 + e] = bfu(hm[r]);
  {
    int row = tid >> 4, k0 = (tid & 15) * 4;
    *(uint2*)&sA[0][row*72 + k0]  = *(const uint2*)(Abf  + (size_t)b*64*4096 + tid*4);
    *(uint2*)&sA2[0][row*72 + k0] = *(const uint2*)(A2bf + (size_t)b*64*4096 + tid*4);
  }
  __syncthreads();
  #pragma unroll 1
  for (int t = 0; t < 64; ++t) {
    int cur = t & 1;
    size_t bt = (size_t)b*64 + t;
    int tn = (t < 63) ? t + 1 : t;
    uint2 pa  = *(const uint2*)(Abf  + ((size_t)b*64 + tn)*4096 + tid*4);
    uint2 pa2 = *(const uint2*)(A2bf + ((size_t)b*64 + tn)*4096 + tid*4);
    float4 gxv = *(const float4*)(gxg + bt*4096 + e*64 + mrow);
    FU ha[2];
    #pragma unroll
    for (int kt = 0; kt < 2; ++kt)
      ha[kt].q = *(const uint4*)&sHh[(mt*16 + c)*72 + kt*32 + 8*g];
    f32x4 a1 = {0.f,0.f,0.f,0.f}, a2 = {0.f,0.f,0.f,0.f};
    #pragma unroll
    for (int kt = 0; kt < 2; ++kt) {
      a1 = MFMA(ha[kt].v, wf[1][kt][0].v, a1);
      a1 = MFMA(ha[kt].v, wf[1][kt][1].v, a1);
      a2 = MFMA(ha[kt].v, wf[2][kt][0].v, a2);
      a2 = MFMA(ha[kt].v, wf[2][kt][1].v, a2);
    }
    {
      ushort4 o1, o2;
      o1.x = bfu(a1[0]); o1.y = bfu(a1[1]); o1.z = bfu(a1[2]); o1.w = bfu(a1[3]);
      o2.x = bfu(a2[0]); o2.y = bfu(a2[1]); o2.z = bfu(a2[2]); o2.w = bfu(a2[3]);
      *(ushort4*)&sZ1[e*72 + mrow] = o1;
      *(ushort4*)&sZ2[e*72 + mrow] = o2;
    }
    __syncthreads();   // B1
    f32x4 acc = {0.f,0.f,0.f,0.f};
    #pragma unroll
    for (int kt = 0; kt < 2; ++kt) {
      FU aA, aA2, z1f, z2f;
      int ao = (mt*16 + c)*72 + kt*32 + 8*g;
      aA.q  = *(const uint4*)&sA[cur][ao];
      aA2.q = *(const uint4*)&sA2[cur][ao];
      z1f.q = *(const uint4*)&sZ1[e*72 + kt*32 + 8*g];
      z2f.q = *(const uint4*)&sZ2[e*72 + kt*32 + 8*g];
      acc = MFMA(ha[kt].v, wf[0][kt][0].v, acc);
      acc = MFMA(ha[kt].v, wf[0][kt][1].v, acc);
      acc = MFMA(aA.v,  z1f.v, acc);
      acc = MFMA(aA2.v, z2f.v, acc);
    }
    float gxa[4] = {gxv.x, gxv.y, gxv.z, gxv.w};
    float ps = 0.f;
    #pragma unroll
    for (int r = 0; r < 4; ++r) {
      float gc = acc[r] + gxa[r] + bgv;
      float f = tanh_f(gc);
      float hn = hm[r] + DT_C * (-(itau + f) * hm[r] + f * apv);
      hm[r] = hn;
      ps += hn;
      sHh[(mrow+r)*72 + e] = bfu(hn);
    }
    sPart[e*17 + mt*4 + g] = ps;
    {
      int row = tid >> 4, k0 = (tid & 15) * 4;
      *(uint2*)&sA[cur^1][row*72 + k0]  = pa;
      *(uint2*)&sA2[cur^1][row*72 + k0] = pa2;
    }
    __syncthreads();   // B2
    if (lane < 4) {
      int ee = w*4 + lane;
      float s = 0.f;
      #pragma unroll
      for (int j = 0; j < 16; ++j) s += sPart[ee*17 + j];
      mout[bt*64 + ee] = s * (1.0f / 64.0f);
    }
  }
  #pragma unroll
  for (int r = 0; r < 4; ++r)
    out[512 + (size_t)b*4096 + (mrow+r)*64 + e] = hm[r];
}

// ---- decoder MLP for all (b,t) in parallel ----
__global__ __launch_bounds__(128) void dec_k(const float* __restrict__ mout,
                                             const float* __restrict__ Wd1, const float* __restrict__ bd1,
                                             const float* __restrict__ Wd2, const float* __restrict__ bd2,
                                             const float* __restrict__ Wd3, const float* __restrict__ bd3,
                                             float* __restrict__ out) {
  __shared__ float sm[64], sd1[128], sd2[64];
  int bt = blockIdx.x, tid = threadIdx.x;
  if (tid < 64) sm[tid] = mout[(size_t)bt*64 + tid];
  __syncthreads();
  {
    float a = bd1[tid];
    #pragma unroll 8
    for (int e = 0; e < 64; ++e) a += sm[e] * Wd1[e*128 + tid];
    sd1[tid] = fmaxf(a, 0.f);
  }
  __syncthreads();
  if (tid < 64) {
    float a = bd2[tid];
    #pragma unroll 8
    for (int i = 0; i < 128; ++i) a += sd1[i] * Wd2[i*64 + tid];
    sd2[tid] = fmaxf(a, 0.f);
  }
  __syncthreads();
  if (tid < 64) {
    float p = sd2[tid] * Wd3[tid];
    #pragma unroll
    for (int off = 32; off > 0; off >>= 1) p += __shfl_down(p, off, 64);
    if (tid == 0) out[bt] = p + bd3[0];
  }
}

extern "C" void kernel_launch(void* const* d_in, const int* in_sizes, int n_in,
                              void* d_out, int out_size, void* d_ws, size_t ws_size,
                              hipStream_t stream) {
  const float* frames = (const float*)d_in[0];
  const float* adj    = (const float*)d_in[1];
  const float* h0     = (const float*)d_in[2];
  const float* Wc1 = (const float*)d_in[3];  const float* bc1 = (const float*)d_in[4];
  const float* Wc2 = (const float*)d_in[5];  const float* bc2 = (const float*)d_in[6];
  const float* Wc3 = (const float*)d_in[7];  const float* bc3 = (const float*)d_in[8];
  const float* We  = (const float*)d_in[9];  const float* be  = (const float*)d_in[10];
  const float* Wh  = (const float*)d_in[11]; const float* Wx  = (const float*)d_in[12];
  const float* bg  = (const float*)d_in[13]; const float* tau = (const float*)d_in[14];
  const float* Ap  = (const float*)d_in[15];
  const float* Wd1 = (const float*)d_in[16]; const float* bd1 = (const float*)d_in[17];
  const float* Wd2 = (const float*)d_in[18]; const float* bd2 = (const float*)d_in[19];
  const float* Wd3 = (const float*)d_in[20]; const float* bd3 = (const float*)d_in[21];

  float* ws = (float*)d_ws;
  // Workspace map (float offsets; validated R5-R14). c1h region now unused.
  unsigned short* c2h = (unsigned short*)(ws + 16777216);
  unsigned short* W2h = (unsigned short*)(ws + 20971520);
  unsigned short* W2l = (unsigned short*)(ws + 20980736);
  unsigned short* W3h = (unsigned short*)(ws + 20989952);
  unsigned short* W3l = (unsigned short*)(ws + 21026816);
  unsigned short* WTh = (unsigned short*)(ws + 21063680);
  unsigned short* WTl = (unsigned short*)(ws + 21069824);
  unsigned short* WeTh = (unsigned short*)(ws + 21075968);
  unsigned short* WeTl = (unsigned short*)(ws + 21080064);
  unsigned short* WxTh = (unsigned short*)(ws + 21084160);
  unsigned short* WxTl = (unsigned short*)(ws + 21090304);
  unsigned short* W1h  = (unsigned short*)(ws + 21096448);
  unsigned short* W1l  = (unsigned short*)(ws + 21096960);
  float* node = ws + 4194304;
  float* gx   = ws + 6291456;
  unsigned short* Abf  = (unsigned short*)(ws + 8388608);
  unsigned short* A2bf = (unsigned short*)(ws + 9437184);
  float* mo   = ws + 10485760;
  float* out  = (float*)d_out;

  wprep_k <<<492, 256, 0, stream>>>(Wc2, Wc3, Wh, We, Wx, Wc1, W2h, W2l, W3h, W3l,
                                    WTh, WTl, WeTh, WeTl, WxTh, WxTl, W1h, W1l);
  c12_k   <<<512, 512, 0, stream>>>(frames, W1h, W1l, bc1, W2h, W2l, bc2, c2h);
  conv3e_k<<<512, 256, 0, stream>>>(c2h, W3h, W3l, bc3, WeTh, WeTl, be, node);
  prepm_k <<<512, 512, 0, stream>>>(adj, node, WxTh, WxTl, Abf, A2bf, gx);
  seq2_k  <<<8,  1024, 0, stream>>>(Abf, A2bf, gx, h0, WTh, WTl, bg, tau, Ap, mo, out);
  dec_k   <<<512, 128, 0, stream>>>(mo, Wd1, bd1, Wd2, bd2, Wd3, bd3, out);
}